// Round 15
// baseline (126.749 us; speedup 1.0000x reference)
//
#include <hip/hip_runtime.h>
#include <math.h>

// ---------------------------------------------------------------------------
// ArithmeticNps: B=16384, CV=128, CR=64, NR=16, CM_RULE=128
//   setup_tables : 2 blocks, LDS-staged operand matrices (bitwise-exact).
//   mega         : 96 fold blocks (W1h, W2d) + B/32 stage1 blocks.
//   stage2       : 32 elems/block, TWO-buffer A/H (34KB total, no
//                  live-across-barrier accumulators -> no scratch spill;
//                  round-14's single-buffer version spilled acc to HBM).
//                  ~512 working blocks -> 2+/CU for latency hiding.
// ---------------------------------------------------------------------------

#define OFF_S1    0        // 1024
#define OFF_T1    1024     // 16
#define OFF_T1OP  1040     // 64
#define OFF_U2    1104     // 64
#define OFF_V2    1168     // 4096
#define OFF_W1H   5264     // 16*128*128 = 262144
#define OFF_B1H   267408   // 2048
#define OFF_W2D   269456   // 16*128*64 = 131072
#define OFF_B2D   400528   // 1024
#define OFF_VARH  401552   // B*128

// ---------------------------------------------------------------------------
__global__ __launch_bounds__(256) void setup_tables(
    const float* __restrict__ rules_emb, const float* __restrict__ s1_k_w,
    const float* __restrict__ s1_k_b,   const float* __restrict__ s2_k_w,
    const float* __restrict__ s2_k_b,
    const float* __restrict__ enc_opr_w1, const float* __restrict__ enc_opr_b1,
    const float* __restrict__ enc_opr_w2, const float* __restrict__ enc_opr_b2,
    const float* __restrict__ enc_op_w2,  const float* __restrict__ enc_op_b2,
    const float* __restrict__ s1_q_w, const float* __restrict__ s1_q_b,
    const float* __restrict__ s2_q_w, const float* __restrict__ s2_q_b,
    int* __restrict__ cnt, float* __restrict__ fws)
{
    const int t = threadIdx.x;
    __shared__ float sm[15392];

    if (blockIdx.x == 0) {
        float* W2s  = sm;           // 8192  enc_op_w2 (64x128)
        float* QWs  = sm + 8192;    // 4096  s1_q_w   (128x32)
        float* OPEs = sm + 12288;   // 384
        float* R1s  = sm + 12672;   // 512
        float* C1s  = sm + 13184;   // 32
        float* WOPs = sm + 13216;   // 96
        float* M1s  = sm + 13312;   // 2048

        for (int i = t; i < 2048; i += 256)
            ((float4*)W2s)[i] = ((const float4*)enc_op_w2)[i];
        for (int i = t; i < 1024; i += 256)
            ((float4*)QWs)[i] = ((const float4*)s1_q_w)[i];
        __syncthreads();

        for (int idx = t; idx < 384; idx += 256) {
            int v = idx >> 7, c = idx & 127;
            float o = enc_opr_b2[c];
            #pragma unroll 8
            for (int j = 0; j < 64; ++j) {
                float h = fmaxf(enc_opr_w1[v * 64 + j] + enc_opr_b1[j], 0.f);
                o = fmaf(h, enc_opr_w2[j * 128 + c], o);
            }
            OPEs[idx] = o;
        }
        for (int idx = t; idx < 512; idx += 256) {
            int n = idx >> 5;
            float a = s1_k_b[idx];
            #pragma unroll 8
            for (int r = 0; r < 64; ++r)
                a = fmaf(rules_emb[n * 64 + r], s1_k_w[(n * 64 + r) * 32 + (idx & 31)], a);
            R1s[idx] = a;
        }
        for (int idx = t; idx < 32; idx += 256) {
            float a = s1_q_b[idx];
            #pragma unroll 8
            for (int c = 0; c < 128; ++c)
                a = fmaf(enc_op_b2[c], QWs[c * 32 + idx], a);
            C1s[idx] = a;
        }
        for (int idx = t; idx < 2048; idx += 256) {       // M1[j][m]
            int j = idx >> 5, m = idx & 31;
            float a = 0.f;
            #pragma unroll 8
            for (int c = 0; c < 128; ++c)
                a = fmaf(W2s[j * 128 + c], QWs[c * 32 + m], a);
            M1s[idx] = a;
        }
        __syncthreads();
        for (int idx = t; idx < 96; idx += 256) {         // w1ope[v][m]
            int v = idx >> 5, m = idx & 31;
            float a = s1_q_b[m];
            #pragma unroll 8
            for (int c = 0; c < 128; ++c)
                a = fmaf(OPEs[v * 128 + c], QWs[c * 32 + m], a);
            WOPs[idx] = a;
        }
        __syncthreads();
        for (int idx = t; idx < 1024; idx += 256) {       // S1[n][j]
            int n = idx >> 6, j = idx & 63;
            float a = 0.f;
            #pragma unroll 8
            for (int m = 0; m < 32; ++m)
                a = fmaf(R1s[n * 32 + m], M1s[j * 32 + m], a);
            fws[OFF_S1 + idx] = a;
        }
        for (int idx = t; idx < 16; idx += 256) {         // t1[n]
            float a = 0.f;
            #pragma unroll 8
            for (int m = 0; m < 32; ++m)
                a = fmaf(R1s[idx * 32 + m], C1s[m], a);
            fws[OFF_T1 + idx] = a;
        }
        for (int idx = t; idx < 48; idx += 256) {         // t1op[v][n]
            int v = idx / 16, n = idx % 16;
            float a = 0.f;
            #pragma unroll 8
            for (int m = 0; m < 32; ++m)
                a = fmaf(R1s[n * 32 + m], WOPs[v * 32 + m], a);
            fws[OFF_T1OP + idx] = a;
        }
    } else {
        if (t < 16) cnt[t * 32] = 0;

        float* W2s = sm;           // 8192  enc_op_w2
        float* QWs = sm + 8192;    // 4096  s2_q_w (2x128x16)
        float* R2s = sm + 12288;   // 512
        float* C2s = sm + 12800;   // 32
        float* M2s = sm + 12832;   // 2048

        for (int i = t; i < 2048; i += 256)
            ((float4*)W2s)[i] = ((const float4*)enc_op_w2)[i];
        for (int i = t; i < 1024; i += 256)
            ((float4*)QWs)[i] = ((const float4*)s2_q_w)[i];
        __syncthreads();

        for (int idx = t; idx < 512; idx += 256) {
            int r = idx >> 5, n = (idx >> 4) & 1, m = idx & 15;
            float a = s2_k_b[n * 16 + m];
            #pragma unroll 8
            for (int j = 0; j < 64; ++j)
                a = fmaf(rules_emb[r * 64 + j], s2_k_w[(n * 64 + j) * 16 + m], a);
            R2s[idx] = a;
        }
        for (int idx = t; idx < 32; idx += 256) {
            int k = idx >> 4, m = idx & 15;
            float a = s2_q_b[idx];
            #pragma unroll 8
            for (int c = 0; c < 128; ++c)
                a = fmaf(enc_op_b2[c], QWs[(k * 128 + c) * 16 + m], a);
            C2s[idx] = a;
        }
        for (int idx = t; idx < 2048; idx += 256) {       // M2[k][j][m]
            int k = idx >> 10, j = (idx >> 4) & 63, m = idx & 15;
            float a = 0.f;
            #pragma unroll 8
            for (int c = 0; c < 128; ++c)
                a = fmaf(W2s[j * 128 + c], QWs[(k * 128 + c) * 16 + m], a);
            M2s[idx] = a;
        }
        __syncthreads();
        for (int idx = t; idx < 64; idx += 256) {         // u2[nk][r]
            int nk = idx >> 4, r = idx & 15, n = nk >> 1, k = nk & 1;
            float a = 0.f;
            #pragma unroll 8
            for (int m = 0; m < 16; ++m)
                a = fmaf(R2s[r * 32 + n * 16 + m], C2s[k * 16 + m], a);
            fws[OFF_U2 + idx] = a;
        }
        for (int idx = t; idx < 4096; idx += 256) {       // V2[nk][j][r]
            int nk = idx >> 10, j = (idx >> 4) & 63, r = idx & 15;
            int n = nk >> 1, k = nk & 1;
            float a = 0.f;
            #pragma unroll 8
            for (int m = 0; m < 16; ++m)
                a = fmaf(R2s[r * 32 + n * 16 + m], M2s[(k * 64 + j) * 16 + m], a);
            fws[OFF_V2 + idx] = a;
        }
    }
}

// ---------------------------------------------------------------------------
// mega: bx<64 W1h fold; 64<=bx<96 W2d fold; bx>=96 stage1 (blk = bx-96).
__global__ __launch_bounds__(256) void mega(
    const float* __restrict__ op1, const float* __restrict__ op2,
    const int* __restrict__ opr,
    const float* __restrict__ enc_op_w1, const float* __restrict__ enc_op_b1,
    const float* __restrict__ enc_op_w2, const float* __restrict__ enc_op_b2,
    const float* __restrict__ rule_W1,   const float* __restrict__ rule_b1,
    const float* __restrict__ rule_W2,   const float* __restrict__ rule_b2,
    const float* __restrict__ dec_w1,    const float* __restrict__ dec_b1,
    int* __restrict__ cnt, int* __restrict__ bucket,
    float* __restrict__ fws, int B)
{
    const int t = threadIdx.x;

    if (blockIdx.x < 64) {
        const int fb = blockIdx.x;
        const int r = fb >> 2, half = (fb >> 1) & 1, mh = fb & 1;
        const int colg = t & 7, rowg = t >> 3;
        const float* W1src = &rule_W1[((size_t)r * 256 + half * 128) * 128 + mh * 64];

        float acc[2][8];
        #pragma unroll
        for (int i = 0; i < 2; ++i)
            #pragma unroll
            for (int j = 0; j < 8; ++j) acc[i][j] = 0.f;

        #pragma unroll 2
        for (int c = 0; c < 128; ++c) {
            const float4 wa = *(const float4*)&W1src[c * 128 + colg * 8];
            const float4 wb = *(const float4*)&W1src[c * 128 + colg * 8 + 4];
            float w0 = enc_op_w2[(rowg * 2) * 128 + c];
            float w1 = enc_op_w2[(rowg * 2 + 1) * 128 + c];
            acc[0][0] = fmaf(w0, wa.x, acc[0][0]); acc[1][0] = fmaf(w1, wa.x, acc[1][0]);
            acc[0][1] = fmaf(w0, wa.y, acc[0][1]); acc[1][1] = fmaf(w1, wa.y, acc[1][1]);
            acc[0][2] = fmaf(w0, wa.z, acc[0][2]); acc[1][2] = fmaf(w1, wa.z, acc[1][2]);
            acc[0][3] = fmaf(w0, wa.w, acc[0][3]); acc[1][3] = fmaf(w1, wa.w, acc[1][3]);
            acc[0][4] = fmaf(w0, wb.x, acc[0][4]); acc[1][4] = fmaf(w1, wb.x, acc[1][4]);
            acc[0][5] = fmaf(w0, wb.y, acc[0][5]); acc[1][5] = fmaf(w1, wb.y, acc[1][5]);
            acc[0][6] = fmaf(w0, wb.z, acc[0][6]); acc[1][6] = fmaf(w1, wb.z, acc[1][6]);
            acc[0][7] = fmaf(w0, wb.w, acc[0][7]); acc[1][7] = fmaf(w1, wb.w, acc[1][7]);
        }
        #pragma unroll
        for (int i = 0; i < 2; ++i)
            #pragma unroll
            for (int j = 0; j < 8; ++j)
                fws[OFF_W1H + r * 16384 + (half * 64 + rowg * 2 + i) * 128 + mh * 64 + colg * 8 + j] = acc[i][j];

        if ((fb & 3) == 0 && t < 128) {
            const float* W1r = &rule_W1[(size_t)r * 256 * 128];
            float b = rule_b1[r * 128 + t];
            #pragma unroll 4
            for (int c = 0; c < 128; ++c)
                b += enc_op_b2[c] * (W1r[c * 128 + t] + W1r[(128 + c) * 128 + t]);
            fws[OFF_B1H + r * 128 + t] = b;
        }
        return;
    }

    if (blockIdx.x < 96) {
        const int fb = blockIdx.x - 64;
        const int r = fb >> 1, dh = fb & 1;
        const int colg = t & 7, rowg = t >> 3;
        const float* W2r = &rule_W2[(size_t)r * 128 * 128];

        float acc[2][8];
        #pragma unroll
        for (int i = 0; i < 2; ++i)
            #pragma unroll
            for (int j = 0; j < 8; ++j) acc[i][j] = 0.f;

        #pragma unroll 2
        for (int c = 0; c < 128; ++c) {
            const float4 da = *(const float4*)&dec_w1[c * 64 + colg * 8];
            const float4 db = *(const float4*)&dec_w1[c * 64 + colg * 8 + 4];
            float w0 = W2r[(dh * 64 + rowg * 2) * 128 + c];
            float w1 = W2r[(dh * 64 + rowg * 2 + 1) * 128 + c];
            acc[0][0] = fmaf(w0, da.x, acc[0][0]); acc[1][0] = fmaf(w1, da.x, acc[1][0]);
            acc[0][1] = fmaf(w0, da.y, acc[0][1]); acc[1][1] = fmaf(w1, da.y, acc[1][1]);
            acc[0][2] = fmaf(w0, da.z, acc[0][2]); acc[1][2] = fmaf(w1, da.z, acc[1][2]);
            acc[0][3] = fmaf(w0, da.w, acc[0][3]); acc[1][3] = fmaf(w1, da.w, acc[1][3]);
            acc[0][4] = fmaf(w0, db.x, acc[0][4]); acc[1][4] = fmaf(w1, db.x, acc[1][4]);
            acc[0][5] = fmaf(w0, db.y, acc[0][5]); acc[1][5] = fmaf(w1, db.y, acc[1][5]);
            acc[0][6] = fmaf(w0, db.z, acc[0][6]); acc[1][6] = fmaf(w1, db.z, acc[1][6]);
            acc[0][7] = fmaf(w0, db.w, acc[0][7]); acc[1][7] = fmaf(w1, db.w, acc[1][7]);
        }
        #pragma unroll
        for (int i = 0; i < 2; ++i)
            #pragma unroll
            for (int j = 0; j < 8; ++j)
                fws[OFF_W2D + r * 8192 + (dh * 64 + rowg * 2 + i) * 64 + colg * 8 + j] = acc[i][j];

        if (dh == 0 && t < 64) {
            float b = dec_b1[t];
            #pragma unroll 4
            for (int c = 0; c < 128; ++c)
                b = fmaf(rule_b2[r * 128 + c], dec_w1[c * 64 + t], b);
            fws[OFF_B2D + r * 64 + t] = b;
        }
        return;
    }

    // ---- stage1 ----
    const int blk = blockIdx.x - 96;

    __shared__ float S1s[16 * 68];
    __shared__ float h[32][132];
    __shared__ float t1s[16];
    __shared__ float t1ops[48];
    __shared__ float u2s[64];
    __shared__ float bvaln[32][17];
    __shared__ float part2[4][32];
    __shared__ float o1s[32], o2s[32];
    __shared__ int ops_[32], idxr[32], idxp[32], idxc[32];
    __shared__ int lcnt[16], lpos[32], base[16];

    if (t < 32) { o1s[t] = op1[blk * 32 + t]; o2s[t] = op2[blk * 32 + t]; ops_[t] = opr[blk * 32 + t]; }
    if (t < 16) { lcnt[t] = 0; t1s[t] = fws[OFF_T1 + t]; }
    if (t >= 16 && t < 64)  t1ops[t - 16] = fws[OFF_T1OP + (t - 16)];
    if (t >= 64 && t < 128) u2s[t - 64]   = fws[OFF_U2 + (t - 64)];
    for (int i = t; i < 1024; i += 256) S1s[(i >> 6) * 68 + (i & 63)] = fws[OFF_S1 + i];
    __syncthreads();

    for (int i = t; i < 4096; i += 256) {
        int e = i >> 7, j = i & 127;
        if (j < 64) {
            h[e][j] = fmaxf(fmaf(o1s[e], enc_op_w1[j], enc_op_b1[j]), 0.f);
        } else {
            int j2 = j - 64;
            h[e][j] = fmaxf(fmaf(o2s[e], enc_op_w1[j2], enc_op_w1[64 + j2] + enc_op_b1[j2]), 0.f);
        }
    }
    __syncthreads();

    #pragma unroll
    for (int pp = 0; pp < 2; ++pp) {
        int p = t + pp * 256;
        int e = p >> 4, n = p & 15;
        float a0 = 0.f, a1 = 0.f;
        #pragma unroll 4
        for (int j4 = 0; j4 < 16; ++j4) {
            float4 s  = *(const float4*)&S1s[n * 68 + j4 * 4];
            float4 h0 = *(const float4*)&h[e][j4 * 4];
            float4 h1 = *(const float4*)&h[e][64 + j4 * 4];
            a0 = fmaf(h0.x, s.x, a0); a0 = fmaf(h0.y, s.y, a0);
            a0 = fmaf(h0.z, s.z, a0); a0 = fmaf(h0.w, s.w, a0);
            a1 = fmaf(h1.x, s.x, a1); a1 = fmaf(h1.y, s.y, a1);
            a1 = fmaf(h1.z, s.z, a1); a1 = fmaf(h1.w, s.w, a1);
        }
        bvaln[e][n] = fmaxf(t1s[n] + fmaxf(a0, a1), t1ops[ops_[e] * 16 + n]);
    }
    __syncthreads();

    if (t < 32) {
        float best = -INFINITY; int bn = 0;
        for (int n = 0; n < 16; ++n) {
            float v = bvaln[t][n];
            if (v > best) { best = v; bn = n; }
        }
        idxr[t] = bn;
    }
    __syncthreads();

    if (t < 128) {
        const int e = t & 31, nk = t >> 5, k = nk & 1;
        const int r = idxr[e];
        const float* v2p = &fws[OFF_V2 + nk * 1024 + r];
        float a = 0.f;
        #pragma unroll 4
        for (int j = 0; j < 64; ++j)
            a = fmaf(h[e][k * 64 + j], v2p[j * 16], a);
        part2[nk][e] = a + u2s[nk * 16 + r];
    }
    __syncthreads();
    if (t < 32) {
        idxp[t] = (part2[1][t] > part2[0][t]) ? 1 : 0;
        idxc[t] = (part2[3][t] > part2[2][t]) ? 1 : 0;
    }
    __syncthreads();

    for (int i = t; i < 1024; i += 256) {
        int e = i >> 5, v4 = i & 31;
        int sel = (v4 < 16) ? idxp[e] : idxc[e];
        float4 val = *(const float4*)&h[e][sel * 64 + (v4 & 15) * 4];
        *(float4*)&fws[OFF_VARH + (size_t)(blk * 32 + e) * 128 + v4 * 4] = val;
    }

    if (t < 32) lpos[t] = atomicAdd(&lcnt[idxr[t]], 1);
    __syncthreads();
    if (t < 16 && lcnt[t] > 0) base[t] = atomicAdd(&cnt[t * 32], lcnt[t]);
    __syncthreads();
    if (t < 32) {
        int r = idxr[t];
        bucket[r * B + base[r] + lpos[t]] = blk * 32 + t;
    }
}

// ---------------------------------------------------------------------------
// 32 elems/block, two-buffer A/H (34KB total, no spill). GEMM1 (2 rows/thr)
// -> GEMM2b (1 row/thr) -> wave-butterfly dot.
__global__ __launch_bounds__(256) void stage2(
    const float* __restrict__ dec_w2, const float* __restrict__ dec_b2,
    const int* __restrict__ cnt, const int* __restrict__ bucket,
    const float* __restrict__ fws, float* __restrict__ out, int B)
{
    const int rule  = blockIdx.y;
    const int start = blockIdx.x * 32;
    const int count = cnt[rule * 32];
    if (start >= count) return;
    const int nelem = min(32, count - start);
    const int t = threadIdx.x;

    __shared__ float A[32][132];
    __shared__ float H[32][132];
    __shared__ int gi[32];

    if (t < 32) gi[t] = bucket[rule * B + start + ((t < nelem) ? t : 0)];
    __syncthreads();
    for (int i = t; i < 32 * 32; i += 256) {
        int e = i >> 5, v = i & 31;
        *(float4*)&A[e][v * 4] = *(const float4*)&fws[OFF_VARH + (size_t)gi[e] * 128 + v * 4];
    }
    __syncthreads();

    // ---- GEMM1: H = relu(A(32x128) @ W1h[rule](128x128) + b1h)
    {
        const int colg = t & 15, rowg = t >> 4;   // 2 rows each
        const float* W1  = &fws[OFF_W1H + rule * 16384 + colg * 8];
        const float* b1p = &fws[OFF_B1H + rule * 128 + colg * 8];
        float acc[2][8];
        #pragma unroll
        for (int j = 0; j < 8; ++j) { acc[0][j] = b1p[j]; acc[1][j] = b1p[j]; }
        #pragma unroll 2
        for (int k = 0; k < 128; ++k) {
            const float4 wa = *(const float4*)&W1[k * 128];
            const float4 wb = *(const float4*)&W1[k * 128 + 4];
            float a0 = A[rowg * 2][k], a1 = A[rowg * 2 + 1][k];
            acc[0][0] = fmaf(a0, wa.x, acc[0][0]); acc[1][0] = fmaf(a1, wa.x, acc[1][0]);
            acc[0][1] = fmaf(a0, wa.y, acc[0][1]); acc[1][1] = fmaf(a1, wa.y, acc[1][1]);
            acc[0][2] = fmaf(a0, wa.z, acc[0][2]); acc[1][2] = fmaf(a1, wa.z, acc[1][2]);
            acc[0][3] = fmaf(a0, wa.w, acc[0][3]); acc[1][3] = fmaf(a1, wa.w, acc[1][3]);
            acc[0][4] = fmaf(a0, wb.x, acc[0][4]); acc[1][4] = fmaf(a1, wb.x, acc[1][4]);
            acc[0][5] = fmaf(a0, wb.y, acc[0][5]); acc[1][5] = fmaf(a1, wb.y, acc[1][5]);
            acc[0][6] = fmaf(a0, wb.z, acc[0][6]); acc[1][6] = fmaf(a1, wb.z, acc[1][6]);
            acc[0][7] = fmaf(a0, wb.w, acc[0][7]); acc[1][7] = fmaf(a1, wb.w, acc[1][7]);
        }
        #pragma unroll
        for (int i = 0; i < 2; ++i)
            #pragma unroll
            for (int j = 0; j < 8; ++j)
                H[rowg * 2 + i][colg * 8 + j] = fmaxf(acc[i][j], 0.f);
    }
    __syncthreads();

    // ---- GEMM2b: A[e][0..63] = relu(H(32x128) @ W2d[rule](128x64) + b2d)
    // (A writes race nothing: all A reads retired before GEMM1's barrier.)
    {
        const int colg = t & 7, rowg = t >> 3;    // 1 row each
        const float* W2  = &fws[OFF_W2D + rule * 8192 + colg * 8];
        const float* b2p = &fws[OFF_B2D + rule * 64 + colg * 8];
        float acc[8];
        #pragma unroll
        for (int j = 0; j < 8; ++j) acc[j] = b2p[j];
        #pragma unroll 4
        for (int k = 0; k < 128; ++k) {
            const float4 wa = *(const float4*)&W2[k * 64];
            const float4 wb = *(const float4*)&W2[k * 64 + 4];
            float h0 = H[rowg][k];
            acc[0] = fmaf(h0, wa.x, acc[0]);
            acc[1] = fmaf(h0, wa.y, acc[1]);
            acc[2] = fmaf(h0, wa.z, acc[2]);
            acc[3] = fmaf(h0, wa.w, acc[3]);
            acc[4] = fmaf(h0, wb.x, acc[4]);
            acc[5] = fmaf(h0, wb.y, acc[5]);
            acc[6] = fmaf(h0, wb.z, acc[6]);
            acc[7] = fmaf(h0, wb.w, acc[7]);
        }
        #pragma unroll
        for (int j = 0; j < 8; ++j)
            A[rowg][colg * 8 + j] = fmaxf(acc[j], 0.f);   // relu(out2)
    }
    __syncthreads();

    // ---- final: out = relu_out2 . dec_w2 + dec_b2 (wave butterfly)
    {
        const int wv = t >> 6, lane = t & 63;
        const float w2v = dec_w2[lane];
        const float b2v = dec_b2[0];
        for (int i = 0; i < 8; ++i) {
            int e = wv * 8 + i;
            if (e >= nelem) break;
            float v = A[e][lane] * w2v;
            #pragma unroll
            for (int off = 32; off; off >>= 1) v += __shfl_down(v, off);
            if (lane == 0) out[gi[e]] = v + b2v;
        }
    }
}

// ---------------------------------------------------------------------------
extern "C" void kernel_launch(void* const* d_in, const int* in_sizes, int n_in,
                              void* d_out, int out_size, void* d_ws, size_t ws_size,
                              hipStream_t stream)
{
    const float* op1        = (const float*)d_in[0];
    const float* op2        = (const float*)d_in[1];
    const int*   opr        = (const int*)  d_in[2];
    const float* enc_op_w1  = (const float*)d_in[3];
    const float* enc_op_b1  = (const float*)d_in[4];
    const float* enc_op_w2  = (const float*)d_in[5];
    const float* enc_op_b2  = (const float*)d_in[6];
    const float* enc_opr_w1 = (const float*)d_in[7];
    const float* enc_opr_b1 = (const float*)d_in[8];
    const float* enc_opr_w2 = (const float*)d_in[9];
    const float* enc_opr_b2 = (const float*)d_in[10];
    const float* dec_w1     = (const float*)d_in[11];
    const float* dec_b1     = (const float*)d_in[12];
    const float* dec_w2     = (const float*)d_in[13];
    const float* dec_b2     = (const float*)d_in[14];
    const float* rules_emb  = (const float*)d_in[15];
    const float* rule_W1    = (const float*)d_in[16];
    const float* rule_b1    = (const float*)d_in[17];
    const float* rule_W2    = (const float*)d_in[18];
    const float* rule_b2    = (const float*)d_in[19];
    const float* s1_q_w     = (const float*)d_in[20];
    const float* s1_q_b     = (const float*)d_in[21];
    const float* s1_k_w     = (const float*)d_in[22];
    const float* s1_k_b     = (const float*)d_in[23];
    const float* s2_q_w     = (const float*)d_in[24];
    const float* s2_q_b     = (const float*)d_in[25];
    const float* s2_k_w     = (const float*)d_in[26];
    const float* s2_k_b     = (const float*)d_in[27];

    float* out = (float*)d_out;
    const int B = in_sizes[0];

    int*   cnt    = (int*)d_ws;                 // 16*32 padded counters
    int*   bucket = cnt + 16 * 32;              // 16*B
    float* fws    = (float*)(bucket + 16 * B);  // float region (16B aligned)

    setup_tables<<<2, 256, 0, stream>>>(
        rules_emb, s1_k_w, s1_k_b, s2_k_w, s2_k_b,
        enc_opr_w1, enc_opr_b1, enc_opr_w2, enc_opr_b2,
        enc_op_w2, enc_op_b2, s1_q_w, s1_q_b, s2_q_w, s2_q_b, cnt, fws);

    mega<<<96 + B / 32, 256, 0, stream>>>(
        op1, op2, opr, enc_op_w1, enc_op_b1, enc_op_w2, enc_op_b2,
        rule_W1, rule_b1, rule_W2, rule_b2, dec_w1, dec_b1,
        cnt, bucket, fws, B);

    stage2<<<dim3(B / 32, 16), 256, 0, stream>>>(
        dec_w2, dec_b2, cnt, bucket, fws, out, B);
}

// Round 17
// 95.449 us; speedup vs baseline: 1.3279x; 1.3279x over previous
//
#include <hip/hip_runtime.h>
#include <math.h>

// ---------------------------------------------------------------------------
// ArithmeticNps: B=16384, CV=128, CR=64, NR=16, CM_RULE=128
//   setup_tables : 2 blocks, LDS-staged operand matrices (bitwise-exact).
//   mega         : 96 fold blocks (W1h, W2d) + B/32 stage1 blocks.
//   stage2       : 64 elems/block; weights LDS-staged in 16-k panels
//                  (8KB buffer, coalesced bulk loads) -> no per-thread L2
//                  latency chains. __launch_bounds__(256,2) so acc[4][8]
//                  lives across panel barriers without spilling (r14 bug:
//                  compiler capped VGPR=52 -> scratch spill -> 7MB HBM).
// ---------------------------------------------------------------------------

#define OFF_S1    0        // 1024
#define OFF_T1    1024     // 16
#define OFF_T1OP  1040     // 64
#define OFF_U2    1104     // 64
#define OFF_V2    1168     // 4096
#define OFF_W1H   5264     // 16*128*128 = 262144
#define OFF_B1H   267408   // 2048
#define OFF_W2D   269456   // 16*128*64 = 131072
#define OFF_B2D   400528   // 1024
#define OFF_VARH  401552   // B*128

// ---------------------------------------------------------------------------
__global__ __launch_bounds__(256) void setup_tables(
    const float* __restrict__ rules_emb, const float* __restrict__ s1_k_w,
    const float* __restrict__ s1_k_b,   const float* __restrict__ s2_k_w,
    const float* __restrict__ s2_k_b,
    const float* __restrict__ enc_opr_w1, const float* __restrict__ enc_opr_b1,
    const float* __restrict__ enc_opr_w2, const float* __restrict__ enc_opr_b2,
    const float* __restrict__ enc_op_w2,  const float* __restrict__ enc_op_b2,
    const float* __restrict__ s1_q_w, const float* __restrict__ s1_q_b,
    const float* __restrict__ s2_q_w, const float* __restrict__ s2_q_b,
    int* __restrict__ cnt, float* __restrict__ fws)
{
    const int t = threadIdx.x;
    __shared__ float sm[15392];

    if (blockIdx.x == 0) {
        float* W2s  = sm;           // 8192  enc_op_w2 (64x128)
        float* QWs  = sm + 8192;    // 4096  s1_q_w   (128x32)
        float* OPEs = sm + 12288;   // 384
        float* R1s  = sm + 12672;   // 512
        float* C1s  = sm + 13184;   // 32
        float* WOPs = sm + 13216;   // 96
        float* M1s  = sm + 13312;   // 2048

        for (int i = t; i < 2048; i += 256)
            ((float4*)W2s)[i] = ((const float4*)enc_op_w2)[i];
        for (int i = t; i < 1024; i += 256)
            ((float4*)QWs)[i] = ((const float4*)s1_q_w)[i];
        __syncthreads();

        for (int idx = t; idx < 384; idx += 256) {
            int v = idx >> 7, c = idx & 127;
            float o = enc_opr_b2[c];
            #pragma unroll 8
            for (int j = 0; j < 64; ++j) {
                float h = fmaxf(enc_opr_w1[v * 64 + j] + enc_opr_b1[j], 0.f);
                o = fmaf(h, enc_opr_w2[j * 128 + c], o);
            }
            OPEs[idx] = o;
        }
        for (int idx = t; idx < 512; idx += 256) {
            int n = idx >> 5;
            float a = s1_k_b[idx];
            #pragma unroll 8
            for (int r = 0; r < 64; ++r)
                a = fmaf(rules_emb[n * 64 + r], s1_k_w[(n * 64 + r) * 32 + (idx & 31)], a);
            R1s[idx] = a;
        }
        for (int idx = t; idx < 32; idx += 256) {
            float a = s1_q_b[idx];
            #pragma unroll 8
            for (int c = 0; c < 128; ++c)
                a = fmaf(enc_op_b2[c], QWs[c * 32 + idx], a);
            C1s[idx] = a;
        }
        for (int idx = t; idx < 2048; idx += 256) {       // M1[j][m]
            int j = idx >> 5, m = idx & 31;
            float a = 0.f;
            #pragma unroll 8
            for (int c = 0; c < 128; ++c)
                a = fmaf(W2s[j * 128 + c], QWs[c * 32 + m], a);
            M1s[idx] = a;
        }
        __syncthreads();
        for (int idx = t; idx < 96; idx += 256) {         // w1ope[v][m]
            int v = idx >> 5, m = idx & 31;
            float a = s1_q_b[m];
            #pragma unroll 8
            for (int c = 0; c < 128; ++c)
                a = fmaf(OPEs[v * 128 + c], QWs[c * 32 + m], a);
            WOPs[idx] = a;
        }
        __syncthreads();
        for (int idx = t; idx < 1024; idx += 256) {       // S1[n][j]
            int n = idx >> 6, j = idx & 63;
            float a = 0.f;
            #pragma unroll 8
            for (int m = 0; m < 32; ++m)
                a = fmaf(R1s[n * 32 + m], M1s[j * 32 + m], a);
            fws[OFF_S1 + idx] = a;
        }
        for (int idx = t; idx < 16; idx += 256) {         // t1[n]
            float a = 0.f;
            #pragma unroll 8
            for (int m = 0; m < 32; ++m)
                a = fmaf(R1s[idx * 32 + m], C1s[m], a);
            fws[OFF_T1 + idx] = a;
        }
        for (int idx = t; idx < 48; idx += 256) {         // t1op[v][n]
            int v = idx / 16, n = idx % 16;
            float a = 0.f;
            #pragma unroll 8
            for (int m = 0; m < 32; ++m)
                a = fmaf(R1s[n * 32 + m], WOPs[v * 32 + m], a);
            fws[OFF_T1OP + idx] = a;
        }
    } else {
        if (t < 16) cnt[t * 32] = 0;

        float* W2s = sm;           // 8192  enc_op_w2
        float* QWs = sm + 8192;    // 4096  s2_q_w (2x128x16)
        float* R2s = sm + 12288;   // 512
        float* C2s = sm + 12800;   // 32
        float* M2s = sm + 12832;   // 2048

        for (int i = t; i < 2048; i += 256)
            ((float4*)W2s)[i] = ((const float4*)enc_op_w2)[i];
        for (int i = t; i < 1024; i += 256)
            ((float4*)QWs)[i] = ((const float4*)s2_q_w)[i];
        __syncthreads();

        for (int idx = t; idx < 512; idx += 256) {
            int r = idx >> 5, n = (idx >> 4) & 1, m = idx & 15;
            float a = s2_k_b[n * 16 + m];
            #pragma unroll 8
            for (int j = 0; j < 64; ++j)
                a = fmaf(rules_emb[r * 64 + j], s2_k_w[(n * 64 + j) * 16 + m], a);
            R2s[idx] = a;
        }
        for (int idx = t; idx < 32; idx += 256) {
            int k = idx >> 4, m = idx & 15;
            float a = s2_q_b[idx];
            #pragma unroll 8
            for (int c = 0; c < 128; ++c)
                a = fmaf(enc_op_b2[c], QWs[(k * 128 + c) * 16 + m], a);
            C2s[idx] = a;
        }
        for (int idx = t; idx < 2048; idx += 256) {       // M2[k][j][m]
            int k = idx >> 10, j = (idx >> 4) & 63, m = idx & 15;
            float a = 0.f;
            #pragma unroll 8
            for (int c = 0; c < 128; ++c)
                a = fmaf(W2s[j * 128 + c], QWs[(k * 128 + c) * 16 + m], a);
            M2s[idx] = a;
        }
        __syncthreads();
        for (int idx = t; idx < 64; idx += 256) {         // u2[nk][r]
            int nk = idx >> 4, r = idx & 15, n = nk >> 1, k = nk & 1;
            float a = 0.f;
            #pragma unroll 8
            for (int m = 0; m < 16; ++m)
                a = fmaf(R2s[r * 32 + n * 16 + m], C2s[k * 16 + m], a);
            fws[OFF_U2 + idx] = a;
        }
        for (int idx = t; idx < 4096; idx += 256) {       // V2[nk][j][r]
            int nk = idx >> 10, j = (idx >> 4) & 63, r = idx & 15;
            int n = nk >> 1, k = nk & 1;
            float a = 0.f;
            #pragma unroll 8
            for (int m = 0; m < 16; ++m)
                a = fmaf(R2s[r * 32 + n * 16 + m], M2s[(k * 64 + j) * 16 + m], a);
            fws[OFF_V2 + idx] = a;
        }
    }
}

// ---------------------------------------------------------------------------
// mega: bx<64 W1h fold; 64<=bx<96 W2d fold; bx>=96 stage1 (blk = bx-96).
__global__ __launch_bounds__(256) void mega(
    const float* __restrict__ op1, const float* __restrict__ op2,
    const int* __restrict__ opr,
    const float* __restrict__ enc_op_w1, const float* __restrict__ enc_op_b1,
    const float* __restrict__ enc_op_w2, const float* __restrict__ enc_op_b2,
    const float* __restrict__ rule_W1,   const float* __restrict__ rule_b1,
    const float* __restrict__ rule_W2,   const float* __restrict__ rule_b2,
    const float* __restrict__ dec_w1,    const float* __restrict__ dec_b1,
    int* __restrict__ cnt, int* __restrict__ bucket,
    float* __restrict__ fws, int B)
{
    const int t = threadIdx.x;

    if (blockIdx.x < 64) {
        const int fb = blockIdx.x;
        const int r = fb >> 2, half = (fb >> 1) & 1, mh = fb & 1;
        const int colg = t & 7, rowg = t >> 3;
        const float* W1src = &rule_W1[((size_t)r * 256 + half * 128) * 128 + mh * 64];

        float acc[2][8];
        #pragma unroll
        for (int i = 0; i < 2; ++i)
            #pragma unroll
            for (int j = 0; j < 8; ++j) acc[i][j] = 0.f;

        #pragma unroll 2
        for (int c = 0; c < 128; ++c) {
            const float4 wa = *(const float4*)&W1src[c * 128 + colg * 8];
            const float4 wb = *(const float4*)&W1src[c * 128 + colg * 8 + 4];
            float w0 = enc_op_w2[(rowg * 2) * 128 + c];
            float w1 = enc_op_w2[(rowg * 2 + 1) * 128 + c];
            acc[0][0] = fmaf(w0, wa.x, acc[0][0]); acc[1][0] = fmaf(w1, wa.x, acc[1][0]);
            acc[0][1] = fmaf(w0, wa.y, acc[0][1]); acc[1][1] = fmaf(w1, wa.y, acc[1][1]);
            acc[0][2] = fmaf(w0, wa.z, acc[0][2]); acc[1][2] = fmaf(w1, wa.z, acc[1][2]);
            acc[0][3] = fmaf(w0, wa.w, acc[0][3]); acc[1][3] = fmaf(w1, wa.w, acc[1][3]);
            acc[0][4] = fmaf(w0, wb.x, acc[0][4]); acc[1][4] = fmaf(w1, wb.x, acc[1][4]);
            acc[0][5] = fmaf(w0, wb.y, acc[0][5]); acc[1][5] = fmaf(w1, wb.y, acc[1][5]);
            acc[0][6] = fmaf(w0, wb.z, acc[0][6]); acc[1][6] = fmaf(w1, wb.z, acc[1][6]);
            acc[0][7] = fmaf(w0, wb.w, acc[0][7]); acc[1][7] = fmaf(w1, wb.w, acc[1][7]);
        }
        #pragma unroll
        for (int i = 0; i < 2; ++i)
            #pragma unroll
            for (int j = 0; j < 8; ++j)
                fws[OFF_W1H + r * 16384 + (half * 64 + rowg * 2 + i) * 128 + mh * 64 + colg * 8 + j] = acc[i][j];

        if ((fb & 3) == 0 && t < 128) {
            const float* W1r = &rule_W1[(size_t)r * 256 * 128];
            float b = rule_b1[r * 128 + t];
            #pragma unroll 4
            for (int c = 0; c < 128; ++c)
                b += enc_op_b2[c] * (W1r[c * 128 + t] + W1r[(128 + c) * 128 + t]);
            fws[OFF_B1H + r * 128 + t] = b;
        }
        return;
    }

    if (blockIdx.x < 96) {
        const int fb = blockIdx.x - 64;
        const int r = fb >> 1, dh = fb & 1;
        const int colg = t & 7, rowg = t >> 3;
        const float* W2r = &rule_W2[(size_t)r * 128 * 128];

        float acc[2][8];
        #pragma unroll
        for (int i = 0; i < 2; ++i)
            #pragma unroll
            for (int j = 0; j < 8; ++j) acc[i][j] = 0.f;

        #pragma unroll 2
        for (int c = 0; c < 128; ++c) {
            const float4 da = *(const float4*)&dec_w1[c * 64 + colg * 8];
            const float4 db = *(const float4*)&dec_w1[c * 64 + colg * 8 + 4];
            float w0 = W2r[(dh * 64 + rowg * 2) * 128 + c];
            float w1 = W2r[(dh * 64 + rowg * 2 + 1) * 128 + c];
            acc[0][0] = fmaf(w0, da.x, acc[0][0]); acc[1][0] = fmaf(w1, da.x, acc[1][0]);
            acc[0][1] = fmaf(w0, da.y, acc[0][1]); acc[1][1] = fmaf(w1, da.y, acc[1][1]);
            acc[0][2] = fmaf(w0, da.z, acc[0][2]); acc[1][2] = fmaf(w1, da.z, acc[1][2]);
            acc[0][3] = fmaf(w0, da.w, acc[0][3]); acc[1][3] = fmaf(w1, da.w, acc[1][3]);
            acc[0][4] = fmaf(w0, db.x, acc[0][4]); acc[1][4] = fmaf(w1, db.x, acc[1][4]);
            acc[0][5] = fmaf(w0, db.y, acc[0][5]); acc[1][5] = fmaf(w1, db.y, acc[1][5]);
            acc[0][6] = fmaf(w0, db.z, acc[0][6]); acc[1][6] = fmaf(w1, db.z, acc[1][6]);
            acc[0][7] = fmaf(w0, db.w, acc[0][7]); acc[1][7] = fmaf(w1, db.w, acc[1][7]);
        }
        #pragma unroll
        for (int i = 0; i < 2; ++i)
            #pragma unroll
            for (int j = 0; j < 8; ++j)
                fws[OFF_W2D + r * 8192 + (dh * 64 + rowg * 2 + i) * 64 + colg * 8 + j] = acc[i][j];

        if (dh == 0 && t < 64) {
            float b = dec_b1[t];
            #pragma unroll 4
            for (int c = 0; c < 128; ++c)
                b = fmaf(rule_b2[r * 128 + c], dec_w1[c * 64 + t], b);
            fws[OFF_B2D + r * 64 + t] = b;
        }
        return;
    }

    // ---- stage1 ----
    const int blk = blockIdx.x - 96;

    __shared__ float S1s[16 * 68];
    __shared__ float h[32][132];
    __shared__ float t1s[16];
    __shared__ float t1ops[48];
    __shared__ float u2s[64];
    __shared__ float bvaln[32][17];
    __shared__ float part2[4][32];
    __shared__ float o1s[32], o2s[32];
    __shared__ int ops_[32], idxr[32], idxp[32], idxc[32];
    __shared__ int lcnt[16], lpos[32], base[16];

    if (t < 32) { o1s[t] = op1[blk * 32 + t]; o2s[t] = op2[blk * 32 + t]; ops_[t] = opr[blk * 32 + t]; }
    if (t < 16) { lcnt[t] = 0; t1s[t] = fws[OFF_T1 + t]; }
    if (t >= 16 && t < 64)  t1ops[t - 16] = fws[OFF_T1OP + (t - 16)];
    if (t >= 64 && t < 128) u2s[t - 64]   = fws[OFF_U2 + (t - 64)];
    for (int i = t; i < 1024; i += 256) S1s[(i >> 6) * 68 + (i & 63)] = fws[OFF_S1 + i];
    __syncthreads();

    for (int i = t; i < 4096; i += 256) {
        int e = i >> 7, j = i & 127;
        if (j < 64) {
            h[e][j] = fmaxf(fmaf(o1s[e], enc_op_w1[j], enc_op_b1[j]), 0.f);
        } else {
            int j2 = j - 64;
            h[e][j] = fmaxf(fmaf(o2s[e], enc_op_w1[j2], enc_op_w1[64 + j2] + enc_op_b1[j2]), 0.f);
        }
    }
    __syncthreads();

    #pragma unroll
    for (int pp = 0; pp < 2; ++pp) {
        int p = t + pp * 256;
        int e = p >> 4, n = p & 15;
        float a0 = 0.f, a1 = 0.f;
        #pragma unroll 4
        for (int j4 = 0; j4 < 16; ++j4) {
            float4 s  = *(const float4*)&S1s[n * 68 + j4 * 4];
            float4 h0 = *(const float4*)&h[e][j4 * 4];
            float4 h1 = *(const float4*)&h[e][64 + j4 * 4];
            a0 = fmaf(h0.x, s.x, a0); a0 = fmaf(h0.y, s.y, a0);
            a0 = fmaf(h0.z, s.z, a0); a0 = fmaf(h0.w, s.w, a0);
            a1 = fmaf(h1.x, s.x, a1); a1 = fmaf(h1.y, s.y, a1);
            a1 = fmaf(h1.z, s.z, a1); a1 = fmaf(h1.w, s.w, a1);
        }
        bvaln[e][n] = fmaxf(t1s[n] + fmaxf(a0, a1), t1ops[ops_[e] * 16 + n]);
    }
    __syncthreads();

    if (t < 32) {
        float best = -INFINITY; int bn = 0;
        for (int n = 0; n < 16; ++n) {
            float v = bvaln[t][n];
            if (v > best) { best = v; bn = n; }
        }
        idxr[t] = bn;
    }
    __syncthreads();

    if (t < 128) {
        const int e = t & 31, nk = t >> 5, k = nk & 1;
        const int r = idxr[e];
        const float* v2p = &fws[OFF_V2 + nk * 1024 + r];
        float a = 0.f;
        #pragma unroll 4
        for (int j = 0; j < 64; ++j)
            a = fmaf(h[e][k * 64 + j], v2p[j * 16], a);
        part2[nk][e] = a + u2s[nk * 16 + r];
    }
    __syncthreads();
    if (t < 32) {
        idxp[t] = (part2[1][t] > part2[0][t]) ? 1 : 0;
        idxc[t] = (part2[3][t] > part2[2][t]) ? 1 : 0;
    }
    __syncthreads();

    for (int i = t; i < 1024; i += 256) {
        int e = i >> 5, v4 = i & 31;
        int sel = (v4 < 16) ? idxp[e] : idxc[e];
        float4 val = *(const float4*)&h[e][sel * 64 + (v4 & 15) * 4];
        *(float4*)&fws[OFF_VARH + (size_t)(blk * 32 + e) * 128 + v4 * 4] = val;
    }

    if (t < 32) lpos[t] = atomicAdd(&lcnt[idxr[t]], 1);
    __syncthreads();
    if (t < 16 && lcnt[t] > 0) base[t] = atomicAdd(&cnt[t * 32], lcnt[t]);
    __syncthreads();
    if (t < 32) {
        int r = idxr[t];
        bucket[r * B + base[r] + lpos[t]] = blk * 32 + t;
    }
}

// ---------------------------------------------------------------------------
// 64 elems/block. Weights LDS-staged in 16-k panels (Wp 8KB reused for both
// GEMMs). acc stays in registers across panel barriers; launch_bounds(256,2)
// gives the register budget (no spill). LDS: A 33.8 + H 33.8 + Wp 8.2 = 76KB
// -> 2 blocks/CU.
__global__ __launch_bounds__(256, 2) void stage2(
    const float* __restrict__ dec_w2, const float* __restrict__ dec_b2,
    const int* __restrict__ cnt, const int* __restrict__ bucket,
    const float* __restrict__ fws, float* __restrict__ out, int B)
{
    const int rule  = blockIdx.y;
    const int start = blockIdx.x * 64;
    const int count = cnt[rule * 32];
    if (start >= count) return;
    const int nelem = min(64, count - start);
    const int t = threadIdx.x;

    __shared__ float A[64][132];
    __shared__ float H[64][132];
    __shared__ float Wp[2048];      // 16x128 weight panel (8KB)
    __shared__ int gi[64];

    if (t < 64) gi[t] = bucket[rule * B + start + ((t < nelem) ? t : 0)];
    __syncthreads();
    for (int i = t; i < 64 * 32; i += 256) {
        int e = i >> 5, v = i & 31;
        *(float4*)&A[e][v * 4] = *(const float4*)&fws[OFF_VARH + (size_t)gi[e] * 128 + v * 4];
    }

    // ---- GEMM1: H = relu(A(64x128) @ W1h[rule](128x128) + b1h), k-panels
    {
        const int colg = t & 15, rowg = t >> 4;   // 4 rows each
        const float* W1p = &fws[OFF_W1H + rule * 16384];
        const float* b1p = &fws[OFF_B1H + rule * 128 + colg * 8];
        float acc[4][8];
        #pragma unroll
        for (int i = 0; i < 4; ++i)
            #pragma unroll
            for (int j = 0; j < 8; ++j) acc[i][j] = b1p[j];

        for (int p = 0; p < 8; ++p) {
            __syncthreads();   // Wp free (and p==0: A gather complete)
            {
                const float4* src = (const float4*)(W1p + p * 2048);
                #pragma unroll
                for (int i = 0; i < 2; ++i)
                    ((float4*)Wp)[t + i * 256] = src[t + i * 256];
            }
            __syncthreads();
            #pragma unroll
            for (int kk = 0; kk < 16; ++kk) {
                const int k = p * 16 + kk;
                const float4 wa = *(const float4*)&Wp[kk * 128 + colg * 8];
                const float4 wb = *(const float4*)&Wp[kk * 128 + colg * 8 + 4];
                float a0 = A[rowg * 4][k], a1 = A[rowg * 4 + 1][k];
                float a2 = A[rowg * 4 + 2][k], a3 = A[rowg * 4 + 3][k];
                acc[0][0] = fmaf(a0, wa.x, acc[0][0]); acc[1][0] = fmaf(a1, wa.x, acc[1][0]);
                acc[2][0] = fmaf(a2, wa.x, acc[2][0]); acc[3][0] = fmaf(a3, wa.x, acc[3][0]);
                acc[0][1] = fmaf(a0, wa.y, acc[0][1]); acc[1][1] = fmaf(a1, wa.y, acc[1][1]);
                acc[2][1] = fmaf(a2, wa.y, acc[2][1]); acc[3][1] = fmaf(a3, wa.y, acc[3][1]);
                acc[0][2] = fmaf(a0, wa.z, acc[0][2]); acc[1][2] = fmaf(a1, wa.z, acc[1][2]);
                acc[2][2] = fmaf(a2, wa.z, acc[2][2]); acc[3][2] = fmaf(a3, wa.z, acc[3][2]);
                acc[0][3] = fmaf(a0, wa.w, acc[0][3]); acc[1][3] = fmaf(a1, wa.w, acc[1][3]);
                acc[2][3] = fmaf(a2, wa.w, acc[2][3]); acc[3][3] = fmaf(a3, wa.w, acc[3][3]);
                acc[0][4] = fmaf(a0, wb.x, acc[0][4]); acc[1][4] = fmaf(a1, wb.x, acc[1][4]);
                acc[2][4] = fmaf(a2, wb.x, acc[2][4]); acc[3][4] = fmaf(a3, wb.x, acc[3][4]);
                acc[0][5] = fmaf(a0, wb.y, acc[0][5]); acc[1][5] = fmaf(a1, wb.y, acc[1][5]);
                acc[2][5] = fmaf(a2, wb.y, acc[2][5]); acc[3][5] = fmaf(a3, wb.y, acc[3][5]);
                acc[0][6] = fmaf(a0, wb.z, acc[0][6]); acc[1][6] = fmaf(a1, wb.z, acc[1][6]);
                acc[2][6] = fmaf(a2, wb.z, acc[2][6]); acc[3][6] = fmaf(a3, wb.z, acc[3][6]);
                acc[0][7] = fmaf(a0, wb.w, acc[0][7]); acc[1][7] = fmaf(a1, wb.w, acc[1][7]);
                acc[2][7] = fmaf(a2, wb.w, acc[2][7]); acc[3][7] = fmaf(a3, wb.w, acc[3][7]);
            }
        }
        #pragma unroll
        for (int i = 0; i < 4; ++i)
            #pragma unroll
            for (int j = 0; j < 8; ++j)
                H[rowg * 4 + i][colg * 8 + j] = fmaxf(acc[i][j], 0.f);
    }
    __syncthreads();

    // ---- GEMM2b: A[e][0..63] = relu(H(64x128) @ W2d[rule](128x64) + b2d), k-panels
    {
        const int colg = t & 7, rowg = t >> 3;    // 2 rows each
        const float* W2p = &fws[OFF_W2D + rule * 8192];
        const float* b2p = &fws[OFF_B2D + rule * 64 + colg * 8];
        float acc[2][8];
        #pragma unroll
        for (int j = 0; j < 8; ++j) { acc[0][j] = b2p[j]; acc[1][j] = b2p[j]; }

        for (int p = 0; p < 8; ++p) {
            __syncthreads();   // Wp free (H-write done for p==0 via prior barrier)
            ((float4*)Wp)[t] = ((const float4*)(W2p + p * 1024))[t];   // 16x64 panel
            __syncthreads();
            #pragma unroll
            for (int kk = 0; kk < 16; ++kk) {
                const int k = p * 16 + kk;
                const float4 wa = *(const float4*)&Wp[kk * 64 + colg * 8];
                const float4 wb = *(const float4*)&Wp[kk * 64 + colg * 8 + 4];
                float h0 = H[rowg * 2][k], h1 = H[rowg * 2 + 1][k];
                acc[0][0] = fmaf(h0, wa.x, acc[0][0]); acc[1][0] = fmaf(h1, wa.x, acc[1][0]);
                acc[0][1] = fmaf(h0, wa.y, acc[0][1]); acc[1][1] = fmaf(h1, wa.y, acc[1][1]);
                acc[0][2] = fmaf(h0, wa.z, acc[0][2]); acc[1][2] = fmaf(h1, wa.z, acc[1][2]);
                acc[0][3] = fmaf(h0, wa.w, acc[0][3]); acc[1][3] = fmaf(h1, wa.w, acc[1][3]);
                acc[0][4] = fmaf(h0, wb.x, acc[0][4]); acc[1][4] = fmaf(h1, wb.x, acc[1][4]);
                acc[0][5] = fmaf(h0, wb.y, acc[0][5]); acc[1][5] = fmaf(h1, wb.y, acc[1][5]);
                acc[0][6] = fmaf(h0, wb.z, acc[0][6]); acc[1][6] = fmaf(h1, wb.z, acc[1][6]);
                acc[0][7] = fmaf(h0, wb.w, acc[0][7]); acc[1][7] = fmaf(h1, wb.w, acc[1][7]);
            }
        }
        __syncthreads();   // all A reads long since retired; H reads done
        #pragma unroll
        for (int i = 0; i < 2; ++i)
            #pragma unroll
            for (int j = 0; j < 8; ++j)
                A[rowg * 2 + i][colg * 8 + j] = fmaxf(acc[i][j], 0.f);   // relu(out2)
    }
    __syncthreads();

    // ---- final: out = relu_out2 . dec_w2 + dec_b2 (wave butterfly)
    {
        const int wv = t >> 6, lane = t & 63;
        const float w2v = dec_w2[lane];
        const float b2v = dec_b2[0];
        for (int i = 0; i < 16; ++i) {
            int e = wv * 16 + i;
            if (e >= nelem) break;
            float v = A[e][lane] * w2v;
            #pragma unroll
            for (int off = 32; off; off >>= 1) v += __shfl_down(v, off);
            if (lane == 0) out[gi[e]] = v + b2v;
        }
    }
}

// ---------------------------------------------------------------------------
extern "C" void kernel_launch(void* const* d_in, const int* in_sizes, int n_in,
                              void* d_out, int out_size, void* d_ws, size_t ws_size,
                              hipStream_t stream)
{
    const float* op1        = (const float*)d_in[0];
    const float* op2        = (const float*)d_in[1];
    const int*   opr        = (const int*)  d_in[2];
    const float* enc_op_w1  = (const float*)d_in[3];
    const float* enc_op_b1  = (const float*)d_in[4];
    const float* enc_op_w2  = (const float*)d_in[5];
    const float* enc_op_b2  = (const float*)d_in[6];
    const float* enc_opr_w1 = (const float*)d_in[7];
    const float* enc_opr_b1 = (const float*)d_in[8];
    const float* enc_opr_w2 = (const float*)d_in[9];
    const float* enc_opr_b2 = (const float*)d_in[10];
    const float* dec_w1     = (const float*)d_in[11];
    const float* dec_b1     = (const float*)d_in[12];
    const float* dec_w2     = (const float*)d_in[13];
    const float* dec_b2     = (const float*)d_in[14];
    const float* rules_emb  = (const float*)d_in[15];
    const float* rule_W1    = (const float*)d_in[16];
    const float* rule_b1    = (const float*)d_in[17];
    const float* rule_W2    = (const float*)d_in[18];
    const float* rule_b2    = (const float*)d_in[19];
    const float* s1_q_w     = (const float*)d_in[20];
    const float* s1_q_b     = (const float*)d_in[21];
    const float* s1_k_w     = (const float*)d_in[22];
    const float* s1_k_b     = (const float*)d_in[23];
    const float* s2_q_w     = (const float*)d_in[24];
    const float* s2_q_b     = (const float*)d_in[25];
    const float* s2_k_w     = (const float*)d_in[26];
    const float* s2_k_b     = (const float*)d_in[27];

    float* out = (float*)d_out;
    const int B = in_sizes[0];

    int*   cnt    = (int*)d_ws;                 // 16*32 padded counters
    int*   bucket = cnt + 16 * 32;              // 16*B
    float* fws    = (float*)(bucket + 16 * B);  // float region (16B aligned)

    setup_tables<<<2, 256, 0, stream>>>(
        rules_emb, s1_k_w, s1_k_b, s2_k_w, s2_k_b,
        enc_opr_w1, enc_opr_b1, enc_opr_w2, enc_opr_b2,
        enc_op_w2, enc_op_b2, s1_q_w, s1_q_b, s2_q_w, s2_q_b, cnt, fws);

    mega<<<96 + B / 32, 256, 0, stream>>>(
        op1, op2, opr, enc_op_w1, enc_op_b1, enc_op_w2, enc_op_b2,
        rule_W1, rule_b1, rule_W2, rule_b2, dec_w1, dec_b1,
        cnt, bucket, fws, B);

    stage2<<<dim3(B / 64, 16), 256, 0, stream>>>(
        dec_w2, dec_b2, cnt, bucket, fws, out, B);
}

// Round 18
// 91.878 us; speedup vs baseline: 1.3795x; 1.0389x over previous
//
#include <hip/hip_runtime.h>
#include <math.h>

// ---------------------------------------------------------------------------
// ArithmeticNps: B=16384, CV=128, CR=64, NR=16, CM_RULE=128
//   setup_tables : 2 blocks, LDS-staged operand matrices (bitwise-exact).
//   mega         : 96 fold blocks (W1h, W2d) + B/32 stage1 blocks.
//                  launch_bounds(256,3): r17 showed VGPR=40 strangled the
//                  fold blocks' load pipelining (6% VALU, 10% occ, 43us).
//                  Fold K-loops unroll 4 for 8 in-flight float4 loads.
//   stage2       : 64 elems/block; weights LDS-staged in 16-k panels;
//                  launch_bounds(256,2) so acc[4][8] never spills.
// ---------------------------------------------------------------------------

#define OFF_S1    0        // 1024
#define OFF_T1    1024     // 16
#define OFF_T1OP  1040     // 64
#define OFF_U2    1104     // 64
#define OFF_V2    1168     // 4096
#define OFF_W1H   5264     // 16*128*128 = 262144
#define OFF_B1H   267408   // 2048
#define OFF_W2D   269456   // 16*128*64 = 131072
#define OFF_B2D   400528   // 1024
#define OFF_VARH  401552   // B*128

// ---------------------------------------------------------------------------
__global__ __launch_bounds__(256) void setup_tables(
    const float* __restrict__ rules_emb, const float* __restrict__ s1_k_w,
    const float* __restrict__ s1_k_b,   const float* __restrict__ s2_k_w,
    const float* __restrict__ s2_k_b,
    const float* __restrict__ enc_opr_w1, const float* __restrict__ enc_opr_b1,
    const float* __restrict__ enc_opr_w2, const float* __restrict__ enc_opr_b2,
    const float* __restrict__ enc_op_w2,  const float* __restrict__ enc_op_b2,
    const float* __restrict__ s1_q_w, const float* __restrict__ s1_q_b,
    const float* __restrict__ s2_q_w, const float* __restrict__ s2_q_b,
    int* __restrict__ cnt, float* __restrict__ fws)
{
    const int t = threadIdx.x;
    __shared__ float sm[15392];

    if (blockIdx.x == 0) {
        float* W2s  = sm;           // 8192  enc_op_w2 (64x128)
        float* QWs  = sm + 8192;    // 4096  s1_q_w   (128x32)
        float* OPEs = sm + 12288;   // 384
        float* R1s  = sm + 12672;   // 512
        float* C1s  = sm + 13184;   // 32
        float* WOPs = sm + 13216;   // 96
        float* M1s  = sm + 13312;   // 2048

        for (int i = t; i < 2048; i += 256)
            ((float4*)W2s)[i] = ((const float4*)enc_op_w2)[i];
        for (int i = t; i < 1024; i += 256)
            ((float4*)QWs)[i] = ((const float4*)s1_q_w)[i];
        __syncthreads();

        for (int idx = t; idx < 384; idx += 256) {
            int v = idx >> 7, c = idx & 127;
            float o = enc_opr_b2[c];
            #pragma unroll 8
            for (int j = 0; j < 64; ++j) {
                float h = fmaxf(enc_opr_w1[v * 64 + j] + enc_opr_b1[j], 0.f);
                o = fmaf(h, enc_opr_w2[j * 128 + c], o);
            }
            OPEs[idx] = o;
        }
        for (int idx = t; idx < 512; idx += 256) {
            int n = idx >> 5;
            float a = s1_k_b[idx];
            #pragma unroll 8
            for (int r = 0; r < 64; ++r)
                a = fmaf(rules_emb[n * 64 + r], s1_k_w[(n * 64 + r) * 32 + (idx & 31)], a);
            R1s[idx] = a;
        }
        for (int idx = t; idx < 32; idx += 256) {
            float a = s1_q_b[idx];
            #pragma unroll 8
            for (int c = 0; c < 128; ++c)
                a = fmaf(enc_op_b2[c], QWs[c * 32 + idx], a);
            C1s[idx] = a;
        }
        for (int idx = t; idx < 2048; idx += 256) {       // M1[j][m]
            int j = idx >> 5, m = idx & 31;
            float a = 0.f;
            #pragma unroll 8
            for (int c = 0; c < 128; ++c)
                a = fmaf(W2s[j * 128 + c], QWs[c * 32 + m], a);
            M1s[idx] = a;
        }
        __syncthreads();
        for (int idx = t; idx < 96; idx += 256) {         // w1ope[v][m]
            int v = idx >> 5, m = idx & 31;
            float a = s1_q_b[m];
            #pragma unroll 8
            for (int c = 0; c < 128; ++c)
                a = fmaf(OPEs[v * 128 + c], QWs[c * 32 + m], a);
            WOPs[idx] = a;
        }
        __syncthreads();
        for (int idx = t; idx < 1024; idx += 256) {       // S1[n][j]
            int n = idx >> 6, j = idx & 63;
            float a = 0.f;
            #pragma unroll 8
            for (int m = 0; m < 32; ++m)
                a = fmaf(R1s[n * 32 + m], M1s[j * 32 + m], a);
            fws[OFF_S1 + idx] = a;
        }
        for (int idx = t; idx < 16; idx += 256) {         // t1[n]
            float a = 0.f;
            #pragma unroll 8
            for (int m = 0; m < 32; ++m)
                a = fmaf(R1s[idx * 32 + m], C1s[m], a);
            fws[OFF_T1 + idx] = a;
        }
        for (int idx = t; idx < 48; idx += 256) {         // t1op[v][n]
            int v = idx / 16, n = idx % 16;
            float a = 0.f;
            #pragma unroll 8
            for (int m = 0; m < 32; ++m)
                a = fmaf(R1s[n * 32 + m], WOPs[v * 32 + m], a);
            fws[OFF_T1OP + idx] = a;
        }
    } else {
        if (t < 16) cnt[t * 32] = 0;

        float* W2s = sm;           // 8192  enc_op_w2
        float* QWs = sm + 8192;    // 4096  s2_q_w (2x128x16)
        float* R2s = sm + 12288;   // 512
        float* C2s = sm + 12800;   // 32
        float* M2s = sm + 12832;   // 2048

        for (int i = t; i < 2048; i += 256)
            ((float4*)W2s)[i] = ((const float4*)enc_op_w2)[i];
        for (int i = t; i < 1024; i += 256)
            ((float4*)QWs)[i] = ((const float4*)s2_q_w)[i];
        __syncthreads();

        for (int idx = t; idx < 512; idx += 256) {
            int r = idx >> 5, n = (idx >> 4) & 1, m = idx & 15;
            float a = s2_k_b[n * 16 + m];
            #pragma unroll 8
            for (int j = 0; j < 64; ++j)
                a = fmaf(rules_emb[r * 64 + j], s2_k_w[(n * 64 + j) * 16 + m], a);
            R2s[idx] = a;
        }
        for (int idx = t; idx < 32; idx += 256) {
            int k = idx >> 4, m = idx & 15;
            float a = s2_q_b[idx];
            #pragma unroll 8
            for (int c = 0; c < 128; ++c)
                a = fmaf(enc_op_b2[c], QWs[(k * 128 + c) * 16 + m], a);
            C2s[idx] = a;
        }
        for (int idx = t; idx < 2048; idx += 256) {       // M2[k][j][m]
            int k = idx >> 10, j = (idx >> 4) & 63, m = idx & 15;
            float a = 0.f;
            #pragma unroll 8
            for (int c = 0; c < 128; ++c)
                a = fmaf(W2s[j * 128 + c], QWs[(k * 128 + c) * 16 + m], a);
            M2s[idx] = a;
        }
        __syncthreads();
        for (int idx = t; idx < 64; idx += 256) {         // u2[nk][r]
            int nk = idx >> 4, r = idx & 15, n = nk >> 1, k = nk & 1;
            float a = 0.f;
            #pragma unroll 8
            for (int m = 0; m < 16; ++m)
                a = fmaf(R2s[r * 32 + n * 16 + m], C2s[k * 16 + m], a);
            fws[OFF_U2 + idx] = a;
        }
        for (int idx = t; idx < 4096; idx += 256) {       // V2[nk][j][r]
            int nk = idx >> 10, j = (idx >> 4) & 63, r = idx & 15;
            int n = nk >> 1, k = nk & 1;
            float a = 0.f;
            #pragma unroll 8
            for (int m = 0; m < 16; ++m)
                a = fmaf(R2s[r * 32 + n * 16 + m], M2s[(k * 64 + j) * 16 + m], a);
            fws[OFF_V2 + idx] = a;
        }
    }
}

// ---------------------------------------------------------------------------
// mega: bx<64 W1h fold; 64<=bx<96 W2d fold; bx>=96 stage1 (blk = bx-96).
__global__ __launch_bounds__(256, 3) void mega(
    const float* __restrict__ op1, const float* __restrict__ op2,
    const int* __restrict__ opr,
    const float* __restrict__ enc_op_w1, const float* __restrict__ enc_op_b1,
    const float* __restrict__ enc_op_w2, const float* __restrict__ enc_op_b2,
    const float* __restrict__ rule_W1,   const float* __restrict__ rule_b1,
    const float* __restrict__ rule_W2,   const float* __restrict__ rule_b2,
    const float* __restrict__ dec_w1,    const float* __restrict__ dec_b1,
    int* __restrict__ cnt, int* __restrict__ bucket,
    float* __restrict__ fws, int B)
{
    const int t = threadIdx.x;

    if (blockIdx.x < 64) {
        const int fb = blockIdx.x;
        const int r = fb >> 2, half = (fb >> 1) & 1, mh = fb & 1;
        const int colg = t & 7, rowg = t >> 3;
        const float* W1src = &rule_W1[((size_t)r * 256 + half * 128) * 128 + mh * 64];

        float acc[2][8];
        #pragma unroll
        for (int i = 0; i < 2; ++i)
            #pragma unroll
            for (int j = 0; j < 8; ++j) acc[i][j] = 0.f;

        #pragma unroll 4
        for (int c = 0; c < 128; ++c) {
            const float4 wa = *(const float4*)&W1src[c * 128 + colg * 8];
            const float4 wb = *(const float4*)&W1src[c * 128 + colg * 8 + 4];
            float w0 = enc_op_w2[(rowg * 2) * 128 + c];
            float w1 = enc_op_w2[(rowg * 2 + 1) * 128 + c];
            acc[0][0] = fmaf(w0, wa.x, acc[0][0]); acc[1][0] = fmaf(w1, wa.x, acc[1][0]);
            acc[0][1] = fmaf(w0, wa.y, acc[0][1]); acc[1][1] = fmaf(w1, wa.y, acc[1][1]);
            acc[0][2] = fmaf(w0, wa.z, acc[0][2]); acc[1][2] = fmaf(w1, wa.z, acc[1][2]);
            acc[0][3] = fmaf(w0, wa.w, acc[0][3]); acc[1][3] = fmaf(w1, wa.w, acc[1][3]);
            acc[0][4] = fmaf(w0, wb.x, acc[0][4]); acc[1][4] = fmaf(w1, wb.x, acc[1][4]);
            acc[0][5] = fmaf(w0, wb.y, acc[0][5]); acc[1][5] = fmaf(w1, wb.y, acc[1][5]);
            acc[0][6] = fmaf(w0, wb.z, acc[0][6]); acc[1][6] = fmaf(w1, wb.z, acc[1][6]);
            acc[0][7] = fmaf(w0, wb.w, acc[0][7]); acc[1][7] = fmaf(w1, wb.w, acc[1][7]);
        }
        #pragma unroll
        for (int i = 0; i < 2; ++i)
            #pragma unroll
            for (int j = 0; j < 8; ++j)
                fws[OFF_W1H + r * 16384 + (half * 64 + rowg * 2 + i) * 128 + mh * 64 + colg * 8 + j] = acc[i][j];

        if ((fb & 3) == 0 && t < 128) {
            const float* W1r = &rule_W1[(size_t)r * 256 * 128];
            float b = rule_b1[r * 128 + t];
            #pragma unroll 4
            for (int c = 0; c < 128; ++c)
                b += enc_op_b2[c] * (W1r[c * 128 + t] + W1r[(128 + c) * 128 + t]);
            fws[OFF_B1H + r * 128 + t] = b;
        }
        return;
    }

    if (blockIdx.x < 96) {
        const int fb = blockIdx.x - 64;
        const int r = fb >> 1, dh = fb & 1;
        const int colg = t & 7, rowg = t >> 3;
        const float* W2r = &rule_W2[(size_t)r * 128 * 128];

        float acc[2][8];
        #pragma unroll
        for (int i = 0; i < 2; ++i)
            #pragma unroll
            for (int j = 0; j < 8; ++j) acc[i][j] = 0.f;

        #pragma unroll 4
        for (int c = 0; c < 128; ++c) {
            const float4 da = *(const float4*)&dec_w1[c * 64 + colg * 8];
            const float4 db = *(const float4*)&dec_w1[c * 64 + colg * 8 + 4];
            float w0 = W2r[(dh * 64 + rowg * 2) * 128 + c];
            float w1 = W2r[(dh * 64 + rowg * 2 + 1) * 128 + c];
            acc[0][0] = fmaf(w0, da.x, acc[0][0]); acc[1][0] = fmaf(w1, da.x, acc[1][0]);
            acc[0][1] = fmaf(w0, da.y, acc[0][1]); acc[1][1] = fmaf(w1, da.y, acc[1][1]);
            acc[0][2] = fmaf(w0, da.z, acc[0][2]); acc[1][2] = fmaf(w1, da.z, acc[1][2]);
            acc[0][3] = fmaf(w0, da.w, acc[0][3]); acc[1][3] = fmaf(w1, da.w, acc[1][3]);
            acc[0][4] = fmaf(w0, db.x, acc[0][4]); acc[1][4] = fmaf(w1, db.x, acc[1][4]);
            acc[0][5] = fmaf(w0, db.y, acc[0][5]); acc[1][5] = fmaf(w1, db.y, acc[1][5]);
            acc[0][6] = fmaf(w0, db.z, acc[0][6]); acc[1][6] = fmaf(w1, db.z, acc[1][6]);
            acc[0][7] = fmaf(w0, db.w, acc[0][7]); acc[1][7] = fmaf(w1, db.w, acc[1][7]);
        }
        #pragma unroll
        for (int i = 0; i < 2; ++i)
            #pragma unroll
            for (int j = 0; j < 8; ++j)
                fws[OFF_W2D + r * 8192 + (dh * 64 + rowg * 2 + i) * 64 + colg * 8 + j] = acc[i][j];

        if (dh == 0 && t < 64) {
            float b = dec_b1[t];
            #pragma unroll 4
            for (int c = 0; c < 128; ++c)
                b = fmaf(rule_b2[r * 128 + c], dec_w1[c * 64 + t], b);
            fws[OFF_B2D + r * 64 + t] = b;
        }
        return;
    }

    // ---- stage1 ----
    const int blk = blockIdx.x - 96;

    __shared__ float S1s[16 * 68];
    __shared__ float h[32][132];
    __shared__ float t1s[16];
    __shared__ float t1ops[48];
    __shared__ float u2s[64];
    __shared__ float bvaln[32][17];
    __shared__ float part2[4][32];
    __shared__ float o1s[32], o2s[32];
    __shared__ int ops_[32], idxr[32], idxp[32], idxc[32];
    __shared__ int lcnt[16], lpos[32], base[16];

    if (t < 32) { o1s[t] = op1[blk * 32 + t]; o2s[t] = op2[blk * 32 + t]; ops_[t] = opr[blk * 32 + t]; }
    if (t < 16) { lcnt[t] = 0; t1s[t] = fws[OFF_T1 + t]; }
    if (t >= 16 && t < 64)  t1ops[t - 16] = fws[OFF_T1OP + (t - 16)];
    if (t >= 64 && t < 128) u2s[t - 64]   = fws[OFF_U2 + (t - 64)];
    for (int i = t; i < 1024; i += 256) S1s[(i >> 6) * 68 + (i & 63)] = fws[OFF_S1 + i];
    __syncthreads();

    for (int i = t; i < 4096; i += 256) {
        int e = i >> 7, j = i & 127;
        if (j < 64) {
            h[e][j] = fmaxf(fmaf(o1s[e], enc_op_w1[j], enc_op_b1[j]), 0.f);
        } else {
            int j2 = j - 64;
            h[e][j] = fmaxf(fmaf(o2s[e], enc_op_w1[j2], enc_op_w1[64 + j2] + enc_op_b1[j2]), 0.f);
        }
    }
    __syncthreads();

    #pragma unroll
    for (int pp = 0; pp < 2; ++pp) {
        int p = t + pp * 256;
        int e = p >> 4, n = p & 15;
        float a0 = 0.f, a1 = 0.f;
        #pragma unroll 4
        for (int j4 = 0; j4 < 16; ++j4) {
            float4 s  = *(const float4*)&S1s[n * 68 + j4 * 4];
            float4 h0 = *(const float4*)&h[e][j4 * 4];
            float4 h1 = *(const float4*)&h[e][64 + j4 * 4];
            a0 = fmaf(h0.x, s.x, a0); a0 = fmaf(h0.y, s.y, a0);
            a0 = fmaf(h0.z, s.z, a0); a0 = fmaf(h0.w, s.w, a0);
            a1 = fmaf(h1.x, s.x, a1); a1 = fmaf(h1.y, s.y, a1);
            a1 = fmaf(h1.z, s.z, a1); a1 = fmaf(h1.w, s.w, a1);
        }
        bvaln[e][n] = fmaxf(t1s[n] + fmaxf(a0, a1), t1ops[ops_[e] * 16 + n]);
    }
    __syncthreads();

    if (t < 32) {
        float best = -INFINITY; int bn = 0;
        for (int n = 0; n < 16; ++n) {
            float v = bvaln[t][n];
            if (v > best) { best = v; bn = n; }
        }
        idxr[t] = bn;
    }
    __syncthreads();

    if (t < 128) {
        const int e = t & 31, nk = t >> 5, k = nk & 1;
        const int r = idxr[e];
        const float* v2p = &fws[OFF_V2 + nk * 1024 + r];
        float a = 0.f;
        #pragma unroll 4
        for (int j = 0; j < 64; ++j)
            a = fmaf(h[e][k * 64 + j], v2p[j * 16], a);
        part2[nk][e] = a + u2s[nk * 16 + r];
    }
    __syncthreads();
    if (t < 32) {
        idxp[t] = (part2[1][t] > part2[0][t]) ? 1 : 0;
        idxc[t] = (part2[3][t] > part2[2][t]) ? 1 : 0;
    }
    __syncthreads();

    for (int i = t; i < 1024; i += 256) {
        int e = i >> 5, v4 = i & 31;
        int sel = (v4 < 16) ? idxp[e] : idxc[e];
        float4 val = *(const float4*)&h[e][sel * 64 + (v4 & 15) * 4];
        *(float4*)&fws[OFF_VARH + (size_t)(blk * 32 + e) * 128 + v4 * 4] = val;
    }

    if (t < 32) lpos[t] = atomicAdd(&lcnt[idxr[t]], 1);
    __syncthreads();
    if (t < 16 && lcnt[t] > 0) base[t] = atomicAdd(&cnt[t * 32], lcnt[t]);
    __syncthreads();
    if (t < 32) {
        int r = idxr[t];
        bucket[r * B + base[r] + lpos[t]] = blk * 32 + t;
    }
}

// ---------------------------------------------------------------------------
// 64 elems/block. Weights LDS-staged in 16-k panels (Wp 8KB reused for both
// GEMMs). acc stays in registers across panel barriers; launch_bounds(256,2)
// gives the register budget (no spill). LDS: A 33.8 + H 33.8 + Wp 8.2 = 76KB
// -> 2 blocks/CU.
__global__ __launch_bounds__(256, 2) void stage2(
    const float* __restrict__ dec_w2, const float* __restrict__ dec_b2,
    const int* __restrict__ cnt, const int* __restrict__ bucket,
    const float* __restrict__ fws, float* __restrict__ out, int B)
{
    const int rule  = blockIdx.y;
    const int start = blockIdx.x * 64;
    const int count = cnt[rule * 32];
    if (start >= count) return;
    const int nelem = min(64, count - start);
    const int t = threadIdx.x;

    __shared__ float A[64][132];
    __shared__ float H[64][132];
    __shared__ float Wp[2048];      // 16x128 weight panel (8KB)
    __shared__ int gi[64];

    if (t < 64) gi[t] = bucket[rule * B + start + ((t < nelem) ? t : 0)];
    __syncthreads();
    for (int i = t; i < 64 * 32; i += 256) {
        int e = i >> 5, v = i & 31;
        *(float4*)&A[e][v * 4] = *(const float4*)&fws[OFF_VARH + (size_t)gi[e] * 128 + v * 4];
    }

    // ---- GEMM1: H = relu(A(64x128) @ W1h[rule](128x128) + b1h), k-panels
    {
        const int colg = t & 15, rowg = t >> 4;   // 4 rows each
        const float* W1p = &fws[OFF_W1H + rule * 16384];
        const float* b1p = &fws[OFF_B1H + rule * 128 + colg * 8];
        float acc[4][8];
        #pragma unroll
        for (int i = 0; i < 4; ++i)
            #pragma unroll
            for (int j = 0; j < 8; ++j) acc[i][j] = b1p[j];

        for (int p = 0; p < 8; ++p) {
            __syncthreads();   // Wp free (and p==0: A gather complete)
            {
                const float4* src = (const float4*)(W1p + p * 2048);
                #pragma unroll
                for (int i = 0; i < 2; ++i)
                    ((float4*)Wp)[t + i * 256] = src[t + i * 256];
            }
            __syncthreads();
            #pragma unroll
            for (int kk = 0; kk < 16; ++kk) {
                const int k = p * 16 + kk;
                const float4 wa = *(const float4*)&Wp[kk * 128 + colg * 8];
                const float4 wb = *(const float4*)&Wp[kk * 128 + colg * 8 + 4];
                float a0 = A[rowg * 4][k], a1 = A[rowg * 4 + 1][k];
                float a2 = A[rowg * 4 + 2][k], a3 = A[rowg * 4 + 3][k];
                acc[0][0] = fmaf(a0, wa.x, acc[0][0]); acc[1][0] = fmaf(a1, wa.x, acc[1][0]);
                acc[2][0] = fmaf(a2, wa.x, acc[2][0]); acc[3][0] = fmaf(a3, wa.x, acc[3][0]);
                acc[0][1] = fmaf(a0, wa.y, acc[0][1]); acc[1][1] = fmaf(a1, wa.y, acc[1][1]);
                acc[2][1] = fmaf(a2, wa.y, acc[2][1]); acc[3][1] = fmaf(a3, wa.y, acc[3][1]);
                acc[0][2] = fmaf(a0, wa.z, acc[0][2]); acc[1][2] = fmaf(a1, wa.z, acc[1][2]);
                acc[2][2] = fmaf(a2, wa.z, acc[2][2]); acc[3][2] = fmaf(a3, wa.z, acc[3][2]);
                acc[0][3] = fmaf(a0, wa.w, acc[0][3]); acc[1][3] = fmaf(a1, wa.w, acc[1][3]);
                acc[2][3] = fmaf(a2, wa.w, acc[2][3]); acc[3][3] = fmaf(a3, wa.w, acc[3][3]);
                acc[0][4] = fmaf(a0, wb.x, acc[0][4]); acc[1][4] = fmaf(a1, wb.x, acc[1][4]);
                acc[2][4] = fmaf(a2, wb.x, acc[2][4]); acc[3][4] = fmaf(a3, wb.x, acc[3][4]);
                acc[0][5] = fmaf(a0, wb.y, acc[0][5]); acc[1][5] = fmaf(a1, wb.y, acc[1][5]);
                acc[2][5] = fmaf(a2, wb.y, acc[2][5]); acc[3][5] = fmaf(a3, wb.y, acc[3][5]);
                acc[0][6] = fmaf(a0, wb.z, acc[0][6]); acc[1][6] = fmaf(a1, wb.z, acc[1][6]);
                acc[2][6] = fmaf(a2, wb.z, acc[2][6]); acc[3][6] = fmaf(a3, wb.z, acc[3][6]);
                acc[0][7] = fmaf(a0, wb.w, acc[0][7]); acc[1][7] = fmaf(a1, wb.w, acc[1][7]);
                acc[2][7] = fmaf(a2, wb.w, acc[2][7]); acc[3][7] = fmaf(a3, wb.w, acc[3][7]);
            }
        }
        #pragma unroll
        for (int i = 0; i < 4; ++i)
            #pragma unroll
            for (int j = 0; j < 8; ++j)
                H[rowg * 4 + i][colg * 8 + j] = fmaxf(acc[i][j], 0.f);
    }
    __syncthreads();

    // ---- GEMM2b: A[e][0..63] = relu(H(64x128) @ W2d[rule](128x64) + b2d), k-panels
    {
        const int colg = t & 7, rowg = t >> 3;    // 2 rows each
        const float* W2p = &fws[OFF_W2D + rule * 8192];
        const float* b2p = &fws[OFF_B2D + rule * 64 + colg * 8];
        float acc[2][8];
        #pragma unroll
        for (int j = 0; j < 8; ++j) { acc[0][j] = b2p[j]; acc[1][j] = b2p[j]; }

        for (int p = 0; p < 8; ++p) {
            __syncthreads();   // Wp free (H-write done for p==0 via prior barrier)
            ((float4*)Wp)[t] = ((const float4*)(W2p + p * 1024))[t];   // 16x64 panel
            __syncthreads();
            #pragma unroll
            for (int kk = 0; kk < 16; ++kk) {
                const int k = p * 16 + kk;
                const float4 wa = *(const float4*)&Wp[kk * 64 + colg * 8];
                const float4 wb = *(const float4*)&Wp[kk * 64 + colg * 8 + 4];
                float h0 = H[rowg * 2][k], h1 = H[rowg * 2 + 1][k];
                acc[0][0] = fmaf(h0, wa.x, acc[0][0]); acc[1][0] = fmaf(h1, wa.x, acc[1][0]);
                acc[0][1] = fmaf(h0, wa.y, acc[0][1]); acc[1][1] = fmaf(h1, wa.y, acc[1][1]);
                acc[0][2] = fmaf(h0, wa.z, acc[0][2]); acc[1][2] = fmaf(h1, wa.z, acc[1][2]);
                acc[0][3] = fmaf(h0, wa.w, acc[0][3]); acc[1][3] = fmaf(h1, wa.w, acc[1][3]);
                acc[0][4] = fmaf(h0, wb.x, acc[0][4]); acc[1][4] = fmaf(h1, wb.x, acc[1][4]);
                acc[0][5] = fmaf(h0, wb.y, acc[0][5]); acc[1][5] = fmaf(h1, wb.y, acc[1][5]);
                acc[0][6] = fmaf(h0, wb.z, acc[0][6]); acc[1][6] = fmaf(h1, wb.z, acc[1][6]);
                acc[0][7] = fmaf(h0, wb.w, acc[0][7]); acc[1][7] = fmaf(h1, wb.w, acc[1][7]);
            }
        }
        __syncthreads();   // all A reads long since retired; H reads done
        #pragma unroll
        for (int i = 0; i < 2; ++i)
            #pragma unroll
            for (int j = 0; j < 8; ++j)
                A[rowg * 2 + i][colg * 8 + j] = fmaxf(acc[i][j], 0.f);   // relu(out2)
    }
    __syncthreads();

    // ---- final: out = relu_out2 . dec_w2 + dec_b2 (wave butterfly)
    {
        const int wv = t >> 6, lane = t & 63;
        const float w2v = dec_w2[lane];
        const float b2v = dec_b2[0];
        for (int i = 0; i < 16; ++i) {
            int e = wv * 16 + i;
            if (e >= nelem) break;
            float v = A[e][lane] * w2v;
            #pragma unroll
            for (int off = 32; off; off >>= 1) v += __shfl_down(v, off);
            if (lane == 0) out[gi[e]] = v + b2v;
        }
    }
}

// ---------------------------------------------------------------------------
extern "C" void kernel_launch(void* const* d_in, const int* in_sizes, int n_in,
                              void* d_out, int out_size, void* d_ws, size_t ws_size,
                              hipStream_t stream)
{
    const float* op1        = (const float*)d_in[0];
    const float* op2        = (const float*)d_in[1];
    const int*   opr        = (const int*)  d_in[2];
    const float* enc_op_w1  = (const float*)d_in[3];
    const float* enc_op_b1  = (const float*)d_in[4];
    const float* enc_op_w2  = (const float*)d_in[5];
    const float* enc_op_b2  = (const float*)d_in[6];
    const float* enc_opr_w1 = (const float*)d_in[7];
    const float* enc_opr_b1 = (const float*)d_in[8];
    const float* enc_opr_w2 = (const float*)d_in[9];
    const float* enc_opr_b2 = (const float*)d_in[10];
    const float* dec_w1     = (const float*)d_in[11];
    const float* dec_b1     = (const float*)d_in[12];
    const float* dec_w2     = (const float*)d_in[13];
    const float* dec_b2     = (const float*)d_in[14];
    const float* rules_emb  = (const float*)d_in[15];
    const float* rule_W1    = (const float*)d_in[16];
    const float* rule_b1    = (const float*)d_in[17];
    const float* rule_W2    = (const float*)d_in[18];
    const float* rule_b2    = (const float*)d_in[19];
    const float* s1_q_w     = (const float*)d_in[20];
    const float* s1_q_b     = (const float*)d_in[21];
    const float* s1_k_w     = (const float*)d_in[22];
    const float* s1_k_b     = (const float*)d_in[23];
    const float* s2_q_w     = (const float*)d_in[24];
    const float* s2_q_b     = (const float*)d_in[25];
    const float* s2_k_w     = (const float*)d_in[26];
    const float* s2_k_b     = (const float*)d_in[27];

    float* out = (float*)d_out;
    const int B = in_sizes[0];

    int*   cnt    = (int*)d_ws;                 // 16*32 padded counters
    int*   bucket = cnt + 16 * 32;              // 16*B
    float* fws    = (float*)(bucket + 16 * B);  // float region (16B aligned)

    setup_tables<<<2, 256, 0, stream>>>(
        rules_emb, s1_k_w, s1_k_b, s2_k_w, s2_k_b,
        enc_opr_w1, enc_opr_b1, enc_opr_w2, enc_opr_b2,
        enc_op_w2, enc_op_b2, s1_q_w, s1_q_b, s2_q_w, s2_q_b, cnt, fws);

    mega<<<96 + B / 32, 256, 0, stream>>>(
        op1, op2, opr, enc_op_w1, enc_op_b1, enc_op_w2, enc_op_b2,
        rule_W1, rule_b1, rule_W2, rule_b2, dec_w1, dec_b1,
        cnt, bucket, fws, B);

    stage2<<<dim3(B / 64, 16), 256, 0, stream>>>(
        dec_w2, dec_b2, cnt, bucket, fws, out, B);
}

// Round 19
// 89.216 us; speedup vs baseline: 1.4207x; 1.0298x over previous
//
#include <hip/hip_runtime.h>
#include <math.h>

// ---------------------------------------------------------------------------
// ArithmeticNps: B=16384, CV=128, CR=64, NR=16, CM_RULE=128
//   prep   : 98 blocks, all independent: bx<64 W1h fold, 64<=bx<96 W2d fold,
//            bx==96/97 argmax tables (attent1 / attent2+cnt). Tables used
//            only by stage1; folds only by stage2 -> safe to co-launch.
//            (r18: tables ran serially on 2 CUs while 254 idled.)
//   stage1 : 512 blocks standalone (no fold contention).
//   stage2 : 64 elems/block, k-panel LDS weights, launch_bounds(256,2).
// ---------------------------------------------------------------------------

#define OFF_S1    0        // 1024
#define OFF_T1    1024     // 16
#define OFF_T1OP  1040     // 64
#define OFF_U2    1104     // 64
#define OFF_V2    1168     // 4096
#define OFF_W1H   5264     // 16*128*128 = 262144
#define OFF_B1H   267408   // 2048
#define OFF_W2D   269456   // 16*128*64 = 131072
#define OFF_B2D   400528   // 1024
#define OFF_VARH  401552   // B*128

// ---------------------------------------------------------------------------
__global__ __launch_bounds__(256, 3) void prep(
    const float* __restrict__ rules_emb, const float* __restrict__ s1_k_w,
    const float* __restrict__ s1_k_b,   const float* __restrict__ s2_k_w,
    const float* __restrict__ s2_k_b,
    const float* __restrict__ enc_opr_w1, const float* __restrict__ enc_opr_b1,
    const float* __restrict__ enc_opr_w2, const float* __restrict__ enc_opr_b2,
    const float* __restrict__ enc_op_w2,  const float* __restrict__ enc_op_b2,
    const float* __restrict__ s1_q_w, const float* __restrict__ s1_q_b,
    const float* __restrict__ s2_q_w, const float* __restrict__ s2_q_b,
    const float* __restrict__ rule_W1, const float* __restrict__ rule_b1,
    const float* __restrict__ rule_W2, const float* __restrict__ rule_b2,
    const float* __restrict__ dec_w1,  const float* __restrict__ dec_b1,
    int* __restrict__ cnt, float* __restrict__ fws)
{
    const int t = threadIdx.x;
    __shared__ float sm[15392];

    if (blockIdx.x < 64) {
        // ---- W1h fold: r, half (k-rows), mh (64-col group)
        const int fb = blockIdx.x;
        const int r = fb >> 2, half = (fb >> 1) & 1, mh = fb & 1;
        const int colg = t & 7, rowg = t >> 3;
        const float* W1src = &rule_W1[((size_t)r * 256 + half * 128) * 128 + mh * 64];

        float acc[2][8];
        #pragma unroll
        for (int i = 0; i < 2; ++i)
            #pragma unroll
            for (int j = 0; j < 8; ++j) acc[i][j] = 0.f;

        #pragma unroll 4
        for (int c = 0; c < 128; ++c) {
            const float4 wa = *(const float4*)&W1src[c * 128 + colg * 8];
            const float4 wb = *(const float4*)&W1src[c * 128 + colg * 8 + 4];
            float w0 = enc_op_w2[(rowg * 2) * 128 + c];
            float w1 = enc_op_w2[(rowg * 2 + 1) * 128 + c];
            acc[0][0] = fmaf(w0, wa.x, acc[0][0]); acc[1][0] = fmaf(w1, wa.x, acc[1][0]);
            acc[0][1] = fmaf(w0, wa.y, acc[0][1]); acc[1][1] = fmaf(w1, wa.y, acc[1][1]);
            acc[0][2] = fmaf(w0, wa.z, acc[0][2]); acc[1][2] = fmaf(w1, wa.z, acc[1][2]);
            acc[0][3] = fmaf(w0, wa.w, acc[0][3]); acc[1][3] = fmaf(w1, wa.w, acc[1][3]);
            acc[0][4] = fmaf(w0, wb.x, acc[0][4]); acc[1][4] = fmaf(w1, wb.x, acc[1][4]);
            acc[0][5] = fmaf(w0, wb.y, acc[0][5]); acc[1][5] = fmaf(w1, wb.y, acc[1][5]);
            acc[0][6] = fmaf(w0, wb.z, acc[0][6]); acc[1][6] = fmaf(w1, wb.z, acc[1][6]);
            acc[0][7] = fmaf(w0, wb.w, acc[0][7]); acc[1][7] = fmaf(w1, wb.w, acc[1][7]);
        }
        #pragma unroll
        for (int i = 0; i < 2; ++i)
            #pragma unroll
            for (int j = 0; j < 8; ++j)
                fws[OFF_W1H + r * 16384 + (half * 64 + rowg * 2 + i) * 128 + mh * 64 + colg * 8 + j] = acc[i][j];

        if ((fb & 3) == 0 && t < 128) {
            const float* W1r = &rule_W1[(size_t)r * 256 * 128];
            float b = rule_b1[r * 128 + t];
            #pragma unroll 4
            for (int c = 0; c < 128; ++c)
                b += enc_op_b2[c] * (W1r[c * 128 + t] + W1r[(128 + c) * 128 + t]);
            fws[OFF_B1H + r * 128 + t] = b;
        }
        return;
    }

    if (blockIdx.x < 96) {
        // ---- W2d fold: r, dh (64 d-rows)
        const int fb = blockIdx.x - 64;
        const int r = fb >> 1, dh = fb & 1;
        const int colg = t & 7, rowg = t >> 3;
        const float* W2r = &rule_W2[(size_t)r * 128 * 128];

        float acc[2][8];
        #pragma unroll
        for (int i = 0; i < 2; ++i)
            #pragma unroll
            for (int j = 0; j < 8; ++j) acc[i][j] = 0.f;

        #pragma unroll 4
        for (int c = 0; c < 128; ++c) {
            const float4 da = *(const float4*)&dec_w1[c * 64 + colg * 8];
            const float4 db = *(const float4*)&dec_w1[c * 64 + colg * 8 + 4];
            float w0 = W2r[(dh * 64 + rowg * 2) * 128 + c];
            float w1 = W2r[(dh * 64 + rowg * 2 + 1) * 128 + c];
            acc[0][0] = fmaf(w0, da.x, acc[0][0]); acc[1][0] = fmaf(w1, da.x, acc[1][0]);
            acc[0][1] = fmaf(w0, da.y, acc[0][1]); acc[1][1] = fmaf(w1, da.y, acc[1][1]);
            acc[0][2] = fmaf(w0, da.z, acc[0][2]); acc[1][2] = fmaf(w1, da.z, acc[1][2]);
            acc[0][3] = fmaf(w0, da.w, acc[0][3]); acc[1][3] = fmaf(w1, da.w, acc[1][3]);
            acc[0][4] = fmaf(w0, db.x, acc[0][4]); acc[1][4] = fmaf(w1, db.x, acc[1][4]);
            acc[0][5] = fmaf(w0, db.y, acc[0][5]); acc[1][5] = fmaf(w1, db.y, acc[1][5]);
            acc[0][6] = fmaf(w0, db.z, acc[0][6]); acc[1][6] = fmaf(w1, db.z, acc[1][6]);
            acc[0][7] = fmaf(w0, db.w, acc[0][7]); acc[1][7] = fmaf(w1, db.w, acc[1][7]);
        }
        #pragma unroll
        for (int i = 0; i < 2; ++i)
            #pragma unroll
            for (int j = 0; j < 8; ++j)
                fws[OFF_W2D + r * 8192 + (dh * 64 + rowg * 2 + i) * 64 + colg * 8 + j] = acc[i][j];

        if (dh == 0 && t < 64) {
            float b = dec_b1[t];
            #pragma unroll 4
            for (int c = 0; c < 128; ++c)
                b = fmaf(rule_b2[r * 128 + c], dec_w1[c * 64 + t], b);
            fws[OFF_B2D + r * 64 + t] = b;
        }
        return;
    }

    if (blockIdx.x == 96) {
        // ---------------- attent1 tables: S1, t1, t1op ----------------
        float* W2s  = sm;           // 8192  enc_op_w2 (64x128)
        float* QWs  = sm + 8192;    // 4096  s1_q_w   (128x32)
        float* OPEs = sm + 12288;   // 384
        float* R1s  = sm + 12672;   // 512
        float* C1s  = sm + 13184;   // 32
        float* WOPs = sm + 13216;   // 96
        float* M1s  = sm + 13312;   // 2048

        for (int i = t; i < 2048; i += 256)
            ((float4*)W2s)[i] = ((const float4*)enc_op_w2)[i];
        for (int i = t; i < 1024; i += 256)
            ((float4*)QWs)[i] = ((const float4*)s1_q_w)[i];
        __syncthreads();

        for (int idx = t; idx < 384; idx += 256) {
            int v = idx >> 7, c = idx & 127;
            float o = enc_opr_b2[c];
            #pragma unroll 8
            for (int j = 0; j < 64; ++j) {
                float h = fmaxf(enc_opr_w1[v * 64 + j] + enc_opr_b1[j], 0.f);
                o = fmaf(h, enc_opr_w2[j * 128 + c], o);
            }
            OPEs[idx] = o;
        }
        for (int idx = t; idx < 512; idx += 256) {
            int n = idx >> 5;
            float a = s1_k_b[idx];
            #pragma unroll 8
            for (int r = 0; r < 64; ++r)
                a = fmaf(rules_emb[n * 64 + r], s1_k_w[(n * 64 + r) * 32 + (idx & 31)], a);
            R1s[idx] = a;
        }
        for (int idx = t; idx < 32; idx += 256) {
            float a = s1_q_b[idx];
            #pragma unroll 8
            for (int c = 0; c < 128; ++c)
                a = fmaf(enc_op_b2[c], QWs[c * 32 + idx], a);
            C1s[idx] = a;
        }
        for (int idx = t; idx < 2048; idx += 256) {       // M1[j][m]
            int j = idx >> 5, m = idx & 31;
            float a = 0.f;
            #pragma unroll 8
            for (int c = 0; c < 128; ++c)
                a = fmaf(W2s[j * 128 + c], QWs[c * 32 + m], a);
            M1s[idx] = a;
        }
        __syncthreads();
        for (int idx = t; idx < 96; idx += 256) {         // w1ope[v][m]
            int v = idx >> 5, m = idx & 31;
            float a = s1_q_b[m];
            #pragma unroll 8
            for (int c = 0; c < 128; ++c)
                a = fmaf(OPEs[v * 128 + c], QWs[c * 32 + m], a);
            WOPs[idx] = a;
        }
        __syncthreads();
        for (int idx = t; idx < 1024; idx += 256) {       // S1[n][j]
            int n = idx >> 6, j = idx & 63;
            float a = 0.f;
            #pragma unroll 8
            for (int m = 0; m < 32; ++m)
                a = fmaf(R1s[n * 32 + m], M1s[j * 32 + m], a);
            fws[OFF_S1 + idx] = a;
        }
        for (int idx = t; idx < 16; idx += 256) {         // t1[n]
            float a = 0.f;
            #pragma unroll 8
            for (int m = 0; m < 32; ++m)
                a = fmaf(R1s[idx * 32 + m], C1s[m], a);
            fws[OFF_T1 + idx] = a;
        }
        for (int idx = t; idx < 48; idx += 256) {         // t1op[v][n]
            int v = idx / 16, n = idx % 16;
            float a = 0.f;
            #pragma unroll 8
            for (int m = 0; m < 32; ++m)
                a = fmaf(R1s[n * 32 + m], WOPs[v * 32 + m], a);
            fws[OFF_T1OP + idx] = a;
        }
        return;
    }

    // ---------------- attent2 tables: u2, V2 (+ cnt=0) ----------------
    {
        if (t < 16) cnt[t * 32] = 0;

        float* W2s = sm;           // 8192  enc_op_w2
        float* QWs = sm + 8192;    // 4096  s2_q_w (2x128x16)
        float* R2s = sm + 12288;   // 512
        float* C2s = sm + 12800;   // 32
        float* M2s = sm + 12832;   // 2048

        for (int i = t; i < 2048; i += 256)
            ((float4*)W2s)[i] = ((const float4*)enc_op_w2)[i];
        for (int i = t; i < 1024; i += 256)
            ((float4*)QWs)[i] = ((const float4*)s2_q_w)[i];
        __syncthreads();

        for (int idx = t; idx < 512; idx += 256) {
            int r = idx >> 5, n = (idx >> 4) & 1, m = idx & 15;
            float a = s2_k_b[n * 16 + m];
            #pragma unroll 8
            for (int j = 0; j < 64; ++j)
                a = fmaf(rules_emb[r * 64 + j], s2_k_w[(n * 64 + j) * 16 + m], a);
            R2s[idx] = a;
        }
        for (int idx = t; idx < 32; idx += 256) {
            int k = idx >> 4, m = idx & 15;
            float a = s2_q_b[idx];
            #pragma unroll 8
            for (int c = 0; c < 128; ++c)
                a = fmaf(enc_op_b2[c], QWs[(k * 128 + c) * 16 + m], a);
            C2s[idx] = a;
        }
        for (int idx = t; idx < 2048; idx += 256) {       // M2[k][j][m]
            int k = idx >> 10, j = (idx >> 4) & 63, m = idx & 15;
            float a = 0.f;
            #pragma unroll 8
            for (int c = 0; c < 128; ++c)
                a = fmaf(W2s[j * 128 + c], QWs[(k * 128 + c) * 16 + m], a);
            M2s[idx] = a;
        }
        __syncthreads();
        for (int idx = t; idx < 64; idx += 256) {         // u2[nk][r]
            int nk = idx >> 4, r = idx & 15, n = nk >> 1, k = nk & 1;
            float a = 0.f;
            #pragma unroll 8
            for (int m = 0; m < 16; ++m)
                a = fmaf(R2s[r * 32 + n * 16 + m], C2s[k * 16 + m], a);
            fws[OFF_U2 + idx] = a;
        }
        for (int idx = t; idx < 4096; idx += 256) {       // V2[nk][j][r]
            int nk = idx >> 10, j = (idx >> 4) & 63, r = idx & 15;
            int n = nk >> 1, k = nk & 1;
            float a = 0.f;
            #pragma unroll 8
            for (int m = 0; m < 16; ++m)
                a = fmaf(R2s[r * 32 + n * 16 + m], M2s[(k * 64 + j) * 16 + m], a);
            fws[OFF_V2 + idx] = a;
        }
    }
}

// ---------------------------------------------------------------------------
__global__ __launch_bounds__(256, 3) void stage1(
    const float* __restrict__ op1, const float* __restrict__ op2,
    const int* __restrict__ opr,
    const float* __restrict__ enc_op_w1, const float* __restrict__ enc_op_b1,
    int* __restrict__ cnt, int* __restrict__ bucket,
    float* __restrict__ fws, int B)
{
    const int t = threadIdx.x;
    const int blk = blockIdx.x;

    __shared__ float S1s[16 * 68];
    __shared__ float h[32][132];
    __shared__ float t1s[16];
    __shared__ float t1ops[48];
    __shared__ float u2s[64];
    __shared__ float bvaln[32][17];
    __shared__ float part2[4][32];
    __shared__ float o1s[32], o2s[32];
    __shared__ int ops_[32], idxr[32], idxp[32], idxc[32];
    __shared__ int lcnt[16], lpos[32], base[16];

    if (t < 32) { o1s[t] = op1[blk * 32 + t]; o2s[t] = op2[blk * 32 + t]; ops_[t] = opr[blk * 32 + t]; }
    if (t < 16) { lcnt[t] = 0; t1s[t] = fws[OFF_T1 + t]; }
    if (t >= 16 && t < 64)  t1ops[t - 16] = fws[OFF_T1OP + (t - 16)];
    if (t >= 64 && t < 128) u2s[t - 64]   = fws[OFF_U2 + (t - 64)];
    for (int i = t; i < 1024; i += 256) S1s[(i >> 6) * 68 + (i & 63)] = fws[OFF_S1 + i];
    __syncthreads();

    for (int i = t; i < 4096; i += 256) {
        int e = i >> 7, j = i & 127;
        if (j < 64) {
            h[e][j] = fmaxf(fmaf(o1s[e], enc_op_w1[j], enc_op_b1[j]), 0.f);
        } else {
            int j2 = j - 64;
            h[e][j] = fmaxf(fmaf(o2s[e], enc_op_w1[j2], enc_op_w1[64 + j2] + enc_op_b1[j2]), 0.f);
        }
    }
    __syncthreads();

    #pragma unroll
    for (int pp = 0; pp < 2; ++pp) {
        int p = t + pp * 256;
        int e = p >> 4, n = p & 15;
        float a0 = 0.f, a1 = 0.f;
        #pragma unroll 4
        for (int j4 = 0; j4 < 16; ++j4) {
            float4 s  = *(const float4*)&S1s[n * 68 + j4 * 4];
            float4 h0 = *(const float4*)&h[e][j4 * 4];
            float4 h1 = *(const float4*)&h[e][64 + j4 * 4];
            a0 = fmaf(h0.x, s.x, a0); a0 = fmaf(h0.y, s.y, a0);
            a0 = fmaf(h0.z, s.z, a0); a0 = fmaf(h0.w, s.w, a0);
            a1 = fmaf(h1.x, s.x, a1); a1 = fmaf(h1.y, s.y, a1);
            a1 = fmaf(h1.z, s.z, a1); a1 = fmaf(h1.w, s.w, a1);
        }
        bvaln[e][n] = fmaxf(t1s[n] + fmaxf(a0, a1), t1ops[ops_[e] * 16 + n]);
    }
    __syncthreads();

    if (t < 32) {
        float best = -INFINITY; int bn = 0;
        for (int n = 0; n < 16; ++n) {
            float v = bvaln[t][n];
            if (v > best) { best = v; bn = n; }
        }
        idxr[t] = bn;
    }
    __syncthreads();

    if (t < 128) {
        const int e = t & 31, nk = t >> 5, k = nk & 1;
        const int r = idxr[e];
        const float* v2p = &fws[OFF_V2 + nk * 1024 + r];
        float a = 0.f;
        #pragma unroll 4
        for (int j = 0; j < 64; ++j)
            a = fmaf(h[e][k * 64 + j], v2p[j * 16], a);
        part2[nk][e] = a + u2s[nk * 16 + r];
    }
    __syncthreads();
    if (t < 32) {
        idxp[t] = (part2[1][t] > part2[0][t]) ? 1 : 0;
        idxc[t] = (part2[3][t] > part2[2][t]) ? 1 : 0;
    }
    __syncthreads();

    for (int i = t; i < 1024; i += 256) {
        int e = i >> 5, v4 = i & 31;
        int sel = (v4 < 16) ? idxp[e] : idxc[e];
        float4 val = *(const float4*)&h[e][sel * 64 + (v4 & 15) * 4];
        *(float4*)&fws[OFF_VARH + (size_t)(blk * 32 + e) * 128 + v4 * 4] = val;
    }

    if (t < 32) lpos[t] = atomicAdd(&lcnt[idxr[t]], 1);
    __syncthreads();
    if (t < 16 && lcnt[t] > 0) base[t] = atomicAdd(&cnt[t * 32], lcnt[t]);
    __syncthreads();
    if (t < 32) {
        int r = idxr[t];
        bucket[r * B + base[r] + lpos[t]] = blk * 32 + t;
    }
}

// ---------------------------------------------------------------------------
// 64 elems/block. Weights LDS-staged in 16-k panels (Wp 8KB reused for both
// GEMMs). acc stays in registers across panel barriers; launch_bounds(256,2)
// gives the register budget (no spill).
__global__ __launch_bounds__(256, 2) void stage2(
    const float* __restrict__ dec_w2, const float* __restrict__ dec_b2,
    const int* __restrict__ cnt, const int* __restrict__ bucket,
    const float* __restrict__ fws, float* __restrict__ out, int B)
{
    const int rule  = blockIdx.y;
    const int start = blockIdx.x * 64;
    const int count = cnt[rule * 32];
    if (start >= count) return;
    const int nelem = min(64, count - start);
    const int t = threadIdx.x;

    __shared__ float A[64][132];
    __shared__ float H[64][132];
    __shared__ float Wp[2048];      // 16x128 weight panel (8KB)
    __shared__ int gi[64];

    if (t < 64) gi[t] = bucket[rule * B + start + ((t < nelem) ? t : 0)];
    __syncthreads();
    for (int i = t; i < 64 * 32; i += 256) {
        int e = i >> 5, v = i & 31;
        *(float4*)&A[e][v * 4] = *(const float4*)&fws[OFF_VARH + (size_t)gi[e] * 128 + v * 4];
    }

    // ---- GEMM1: H = relu(A(64x128) @ W1h[rule](128x128) + b1h), k-panels
    {
        const int colg = t & 15, rowg = t >> 4;   // 4 rows each
        const float* W1p = &fws[OFF_W1H + rule * 16384];
        const float* b1p = &fws[OFF_B1H + rule * 128 + colg * 8];
        float acc[4][8];
        #pragma unroll
        for (int i = 0; i < 4; ++i)
            #pragma unroll
            for (int j = 0; j < 8; ++j) acc[i][j] = b1p[j];

        for (int p = 0; p < 8; ++p) {
            __syncthreads();   // Wp free (and p==0: A gather complete)
            {
                const float4* src = (const float4*)(W1p + p * 2048);
                #pragma unroll
                for (int i = 0; i < 2; ++i)
                    ((float4*)Wp)[t + i * 256] = src[t + i * 256];
            }
            __syncthreads();
            #pragma unroll
            for (int kk = 0; kk < 16; ++kk) {
                const int k = p * 16 + kk;
                const float4 wa = *(const float4*)&Wp[kk * 128 + colg * 8];
                const float4 wb = *(const float4*)&Wp[kk * 128 + colg * 8 + 4];
                float a0 = A[rowg * 4][k], a1 = A[rowg * 4 + 1][k];
                float a2 = A[rowg * 4 + 2][k], a3 = A[rowg * 4 + 3][k];
                acc[0][0] = fmaf(a0, wa.x, acc[0][0]); acc[1][0] = fmaf(a1, wa.x, acc[1][0]);
                acc[2][0] = fmaf(a2, wa.x, acc[2][0]); acc[3][0] = fmaf(a3, wa.x, acc[3][0]);
                acc[0][1] = fmaf(a0, wa.y, acc[0][1]); acc[1][1] = fmaf(a1, wa.y, acc[1][1]);
                acc[2][1] = fmaf(a2, wa.y, acc[2][1]); acc[3][1] = fmaf(a3, wa.y, acc[3][1]);
                acc[0][2] = fmaf(a0, wa.z, acc[0][2]); acc[1][2] = fmaf(a1, wa.z, acc[1][2]);
                acc[2][2] = fmaf(a2, wa.z, acc[2][2]); acc[3][2] = fmaf(a3, wa.z, acc[3][2]);
                acc[0][3] = fmaf(a0, wa.w, acc[0][3]); acc[1][3] = fmaf(a1, wa.w, acc[1][3]);
                acc[2][3] = fmaf(a2, wa.w, acc[2][3]); acc[3][3] = fmaf(a3, wa.w, acc[3][3]);
                acc[0][4] = fmaf(a0, wb.x, acc[0][4]); acc[1][4] = fmaf(a1, wb.x, acc[1][4]);
                acc[2][4] = fmaf(a2, wb.x, acc[2][4]); acc[3][4] = fmaf(a3, wb.x, acc[3][4]);
                acc[0][5] = fmaf(a0, wb.y, acc[0][5]); acc[1][5] = fmaf(a1, wb.y, acc[1][5]);
                acc[2][5] = fmaf(a2, wb.y, acc[2][5]); acc[3][5] = fmaf(a3, wb.y, acc[3][5]);
                acc[0][6] = fmaf(a0, wb.z, acc[0][6]); acc[1][6] = fmaf(a1, wb.z, acc[1][6]);
                acc[2][6] = fmaf(a2, wb.z, acc[2][6]); acc[3][6] = fmaf(a3, wb.z, acc[3][6]);
                acc[0][7] = fmaf(a0, wb.w, acc[0][7]); acc[1][7] = fmaf(a1, wb.w, acc[1][7]);
                acc[2][7] = fmaf(a2, wb.w, acc[2][7]); acc[3][7] = fmaf(a3, wb.w, acc[3][7]);
            }
        }
        #pragma unroll
        for (int i = 0; i < 4; ++i)
            #pragma unroll
            for (int j = 0; j < 8; ++j)
                H[rowg * 4 + i][colg * 8 + j] = fmaxf(acc[i][j], 0.f);
    }
    __syncthreads();

    // ---- GEMM2b: A[e][0..63] = relu(H(64x128) @ W2d[rule](128x64) + b2d), k-panels
    {
        const int colg = t & 7, rowg = t >> 3;    // 2 rows each
        const float* W2p = &fws[OFF_W2D + rule * 8192];
        const float* b2p = &fws[OFF_B2D + rule * 64 + colg * 8];
        float acc[2][8];
        #pragma unroll
        for (int j = 0; j < 8; ++j) { acc[0][j] = b2p[j]; acc[1][j] = b2p[j]; }

        for (int p = 0; p < 8; ++p) {
            __syncthreads();   // Wp free (H-write done for p==0 via prior barrier)
            ((float4*)Wp)[t] = ((const float4*)(W2p + p * 1024))[t];   // 16x64 panel
            __syncthreads();
            #pragma unroll
            for (int kk = 0; kk < 16; ++kk) {
                const int k = p * 16 + kk;
                const float4 wa = *(const float4*)&Wp[kk * 64 + colg * 8];
                const float4 wb = *(const float4*)&Wp[kk * 64 + colg * 8 + 4];
                float h0 = H[rowg * 2][k], h1 = H[rowg * 2 + 1][k];
                acc[0][0] = fmaf(h0, wa.x, acc[0][0]); acc[1][0] = fmaf(h1, wa.x, acc[1][0]);
                acc[0][1] = fmaf(h0, wa.y, acc[0][1]); acc[1][1] = fmaf(h1, wa.y, acc[1][1]);
                acc[0][2] = fmaf(h0, wa.z, acc[0][2]); acc[1][2] = fmaf(h1, wa.z, acc[1][2]);
                acc[0][3] = fmaf(h0, wa.w, acc[0][3]); acc[1][3] = fmaf(h1, wa.w, acc[1][3]);
                acc[0][4] = fmaf(h0, wb.x, acc[0][4]); acc[1][4] = fmaf(h1, wb.x, acc[1][4]);
                acc[0][5] = fmaf(h0, wb.y, acc[0][5]); acc[1][5] = fmaf(h1, wb.y, acc[1][5]);
                acc[0][6] = fmaf(h0, wb.z, acc[0][6]); acc[1][6] = fmaf(h1, wb.z, acc[1][6]);
                acc[0][7] = fmaf(h0, wb.w, acc[0][7]); acc[1][7] = fmaf(h1, wb.w, acc[1][7]);
            }
        }
        __syncthreads();   // all A reads long since retired; H reads done
        #pragma unroll
        for (int i = 0; i < 2; ++i)
            #pragma unroll
            for (int j = 0; j < 8; ++j)
                A[rowg * 2 + i][colg * 8 + j] = fmaxf(acc[i][j], 0.f);   // relu(out2)
    }
    __syncthreads();

    // ---- final: out = relu_out2 . dec_w2 + dec_b2 (wave butterfly)
    {
        const int wv = t >> 6, lane = t & 63;
        const float w2v = dec_w2[lane];
        const float b2v = dec_b2[0];
        for (int i = 0; i < 16; ++i) {
            int e = wv * 16 + i;
            if (e >= nelem) break;
            float v = A[e][lane] * w2v;
            #pragma unroll
            for (int off = 32; off; off >>= 1) v += __shfl_down(v, off);
            if (lane == 0) out[gi[e]] = v + b2v;
        }
    }
}

// ---------------------------------------------------------------------------
extern "C" void kernel_launch(void* const* d_in, const int* in_sizes, int n_in,
                              void* d_out, int out_size, void* d_ws, size_t ws_size,
                              hipStream_t stream)
{
    const float* op1        = (const float*)d_in[0];
    const float* op2        = (const float*)d_in[1];
    const int*   opr        = (const int*)  d_in[2];
    const float* enc_op_w1  = (const float*)d_in[3];
    const float* enc_op_b1  = (const float*)d_in[4];
    const float* enc_op_w2  = (const float*)d_in[5];
    const float* enc_op_b2  = (const float*)d_in[6];
    const float* enc_opr_w1 = (const float*)d_in[7];
    const float* enc_opr_b1 = (const float*)d_in[8];
    const float* enc_opr_w2 = (const float*)d_in[9];
    const float* enc_opr_b2 = (const float*)d_in[10];
    const float* dec_w1     = (const float*)d_in[11];
    const float* dec_b1     = (const float*)d_in[12];
    const float* dec_w2     = (const float*)d_in[13];
    const float* dec_b2     = (const float*)d_in[14];
    const float* rules_emb  = (const float*)d_in[15];
    const float* rule_W1    = (const float*)d_in[16];
    const float* rule_b1    = (const float*)d_in[17];
    const float* rule_W2    = (const float*)d_in[18];
    const float* rule_b2    = (const float*)d_in[19];
    const float* s1_q_w     = (const float*)d_in[20];
    const float* s1_q_b     = (const float*)d_in[21];
    const float* s1_k_w     = (const float*)d_in[22];
    const float* s1_k_b     = (const float*)d_in[23];
    const float* s2_q_w     = (const float*)d_in[24];
    const float* s2_q_b     = (const float*)d_in[25];
    const float* s2_k_w     = (const float*)d_in[26];
    const float* s2_k_b     = (const float*)d_in[27];

    float* out = (float*)d_out;
    const int B = in_sizes[0];

    int*   cnt    = (int*)d_ws;                 // 16*32 padded counters
    int*   bucket = cnt + 16 * 32;              // 16*B
    float* fws    = (float*)(bucket + 16 * B);  // float region (16B aligned)

    prep<<<98, 256, 0, stream>>>(
        rules_emb, s1_k_w, s1_k_b, s2_k_w, s2_k_b,
        enc_opr_w1, enc_opr_b1, enc_opr_w2, enc_opr_b2,
        enc_op_w2, enc_op_b2, s1_q_w, s1_q_b, s2_q_w, s2_q_b,
        rule_W1, rule_b1, rule_W2, rule_b2, dec_w1, dec_b1, cnt, fws);

    stage1<<<B / 32, 256, 0, stream>>>(
        op1, op2, opr, enc_op_w1, enc_op_b1, cnt, bucket, fws, B);

    stage2<<<dim3(B / 64, 16), 256, 0, stream>>>(
        dec_w2, dec_b2, cnt, bucket, fws, out, B);
}

// Round 22
// 86.003 us; speedup vs baseline: 1.4738x; 1.0374x over previous
//
#include <hip/hip_runtime.h>
#include <math.h>

// ---------------------------------------------------------------------------
// ArithmeticNps: B=16384, CV=128, CR=64, NR=16, CM_RULE=128
//   prep   : 98 independent blocks: W1h fold / W2d fold / argmax tables.
//   stage1 : 512 blocks, folded-table argmax + var_h + bucketing.
//   stage2 : 64 elems/block. Single AH buffer (A -> H -> out2; safe now:
//            launch_bounds(256,2) prevents r14's acc spill) + DOUBLE-BUFFERED
//            weight panels with reg-staged prefetch (panel load hides under
//            compute). LDS 50KB -> 3 blocks/CU (was 76KB/2); barriers ~halved.
// ---------------------------------------------------------------------------

#define OFF_S1    0        // 1024
#define OFF_T1    1024     // 16
#define OFF_T1OP  1040     // 64
#define OFF_U2    1104     // 64
#define OFF_V2    1168     // 4096
#define OFF_W1H   5264     // 16*128*128 = 262144
#define OFF_B1H   267408   // 2048
#define OFF_W2D   269456   // 16*128*64 = 131072
#define OFF_B2D   400528   // 1024
#define OFF_VARH  401552   // B*128

// ---------------------------------------------------------------------------
__global__ __launch_bounds__(256, 3) void prep(
    const float* __restrict__ rules_emb, const float* __restrict__ s1_k_w,
    const float* __restrict__ s1_k_b,   const float* __restrict__ s2_k_w,
    const float* __restrict__ s2_k_b,
    const float* __restrict__ enc_opr_w1, const float* __restrict__ enc_opr_b1,
    const float* __restrict__ enc_opr_w2, const float* __restrict__ enc_opr_b2,
    const float* __restrict__ enc_op_w2,  const float* __restrict__ enc_op_b2,
    const float* __restrict__ s1_q_w, const float* __restrict__ s1_q_b,
    const float* __restrict__ s2_q_w, const float* __restrict__ s2_q_b,
    const float* __restrict__ rule_W1, const float* __restrict__ rule_b1,
    const float* __restrict__ rule_W2, const float* __restrict__ rule_b2,
    const float* __restrict__ dec_w1,  const float* __restrict__ dec_b1,
    int* __restrict__ cnt, float* __restrict__ fws)
{
    const int t = threadIdx.x;
    __shared__ float sm[15392];

    if (blockIdx.x < 64) {
        // ---- W1h fold: r, half (k-rows), mh (64-col group)
        const int fb = blockIdx.x;
        const int r = fb >> 2, half = (fb >> 1) & 1, mh = fb & 1;
        const int colg = t & 7, rowg = t >> 3;
        const float* W1src = &rule_W1[((size_t)r * 256 + half * 128) * 128 + mh * 64];

        float acc[2][8];
        #pragma unroll
        for (int i = 0; i < 2; ++i)
            #pragma unroll
            for (int j = 0; j < 8; ++j) acc[i][j] = 0.f;

        #pragma unroll 4
        for (int c = 0; c < 128; ++c) {
            const float4 wa = *(const float4*)&W1src[c * 128 + colg * 8];
            const float4 wb = *(const float4*)&W1src[c * 128 + colg * 8 + 4];
            float w0 = enc_op_w2[(rowg * 2) * 128 + c];
            float w1 = enc_op_w2[(rowg * 2 + 1) * 128 + c];
            acc[0][0] = fmaf(w0, wa.x, acc[0][0]); acc[1][0] = fmaf(w1, wa.x, acc[1][0]);
            acc[0][1] = fmaf(w0, wa.y, acc[0][1]); acc[1][1] = fmaf(w1, wa.y, acc[1][1]);
            acc[0][2] = fmaf(w0, wa.z, acc[0][2]); acc[1][2] = fmaf(w1, wa.z, acc[1][2]);
            acc[0][3] = fmaf(w0, wa.w, acc[0][3]); acc[1][3] = fmaf(w1, wa.w, acc[1][3]);
            acc[0][4] = fmaf(w0, wb.x, acc[0][4]); acc[1][4] = fmaf(w1, wb.x, acc[1][4]);
            acc[0][5] = fmaf(w0, wb.y, acc[0][5]); acc[1][5] = fmaf(w1, wb.y, acc[1][5]);
            acc[0][6] = fmaf(w0, wb.z, acc[0][6]); acc[1][6] = fmaf(w1, wb.z, acc[1][6]);
            acc[0][7] = fmaf(w0, wb.w, acc[0][7]); acc[1][7] = fmaf(w1, wb.w, acc[1][7]);
        }
        #pragma unroll
        for (int i = 0; i < 2; ++i)
            #pragma unroll
            for (int j = 0; j < 8; ++j)
                fws[OFF_W1H + r * 16384 + (half * 64 + rowg * 2 + i) * 128 + mh * 64 + colg * 8 + j] = acc[i][j];

        if ((fb & 3) == 0 && t < 128) {
            const float* W1r = &rule_W1[(size_t)r * 256 * 128];
            float b = rule_b1[r * 128 + t];
            #pragma unroll 4
            for (int c = 0; c < 128; ++c)
                b += enc_op_b2[c] * (W1r[c * 128 + t] + W1r[(128 + c) * 128 + t]);
            fws[OFF_B1H + r * 128 + t] = b;
        }
        return;
    }

    if (blockIdx.x < 96) {
        // ---- W2d fold: r, dh (64 d-rows)
        const int fb = blockIdx.x - 64;
        const int r = fb >> 1, dh = fb & 1;
        const int colg = t & 7, rowg = t >> 3;
        const float* W2r = &rule_W2[(size_t)r * 128 * 128];

        float acc[2][8];
        #pragma unroll
        for (int i = 0; i < 2; ++i)
            #pragma unroll
            for (int j = 0; j < 8; ++j) acc[i][j] = 0.f;

        #pragma unroll 4
        for (int c = 0; c < 128; ++c) {
            const float4 da = *(const float4*)&dec_w1[c * 64 + colg * 8];
            const float4 db = *(const float4*)&dec_w1[c * 64 + colg * 8 + 4];
            float w0 = W2r[(dh * 64 + rowg * 2) * 128 + c];
            float w1 = W2r[(dh * 64 + rowg * 2 + 1) * 128 + c];
            acc[0][0] = fmaf(w0, da.x, acc[0][0]); acc[1][0] = fmaf(w1, da.x, acc[1][0]);
            acc[0][1] = fmaf(w0, da.y, acc[0][1]); acc[1][1] = fmaf(w1, da.y, acc[1][1]);
            acc[0][2] = fmaf(w0, da.z, acc[0][2]); acc[1][2] = fmaf(w1, da.z, acc[1][2]);
            acc[0][3] = fmaf(w0, da.w, acc[0][3]); acc[1][3] = fmaf(w1, da.w, acc[1][3]);
            acc[0][4] = fmaf(w0, db.x, acc[0][4]); acc[1][4] = fmaf(w1, db.x, acc[1][4]);
            acc[0][5] = fmaf(w0, db.y, acc[0][5]); acc[1][5] = fmaf(w1, db.y, acc[1][5]);
            acc[0][6] = fmaf(w0, db.z, acc[0][6]); acc[1][6] = fmaf(w1, db.z, acc[1][6]);
            acc[0][7] = fmaf(w0, db.w, acc[0][7]); acc[1][7] = fmaf(w1, db.w, acc[1][7]);
        }
        #pragma unroll
        for (int i = 0; i < 2; ++i)
            #pragma unroll
            for (int j = 0; j < 8; ++j)
                fws[OFF_W2D + r * 8192 + (dh * 64 + rowg * 2 + i) * 64 + colg * 8 + j] = acc[i][j];

        if (dh == 0 && t < 64) {
            float b = dec_b1[t];
            #pragma unroll 4
            for (int c = 0; c < 128; ++c)
                b = fmaf(rule_b2[r * 128 + c], dec_w1[c * 64 + t], b);
            fws[OFF_B2D + r * 64 + t] = b;
        }
        return;
    }

    if (blockIdx.x == 96) {
        // ---------------- attent1 tables: S1, t1, t1op ----------------
        float* W2s  = sm;           // 8192  enc_op_w2 (64x128)
        float* QWs  = sm + 8192;    // 4096  s1_q_w   (128x32)
        float* OPEs = sm + 12288;   // 384
        float* R1s  = sm + 12672;   // 512
        float* C1s  = sm + 13184;   // 32
        float* WOPs = sm + 13216;   // 96
        float* M1s  = sm + 13312;   // 2048

        for (int i = t; i < 2048; i += 256)
            ((float4*)W2s)[i] = ((const float4*)enc_op_w2)[i];
        for (int i = t; i < 1024; i += 256)
            ((float4*)QWs)[i] = ((const float4*)s1_q_w)[i];
        __syncthreads();

        for (int idx = t; idx < 384; idx += 256) {
            int v = idx >> 7, c = idx & 127;
            float o = enc_opr_b2[c];
            #pragma unroll 8
            for (int j = 0; j < 64; ++j) {
                float h = fmaxf(enc_opr_w1[v * 64 + j] + enc_opr_b1[j], 0.f);
                o = fmaf(h, enc_opr_w2[j * 128 + c], o);
            }
            OPEs[idx] = o;
        }
        for (int idx = t; idx < 512; idx += 256) {
            int n = idx >> 5;
            float a = s1_k_b[idx];
            #pragma unroll 8
            for (int r = 0; r < 64; ++r)
                a = fmaf(rules_emb[n * 64 + r], s1_k_w[(n * 64 + r) * 32 + (idx & 31)], a);
            R1s[idx] = a;
        }
        for (int idx = t; idx < 32; idx += 256) {
            float a = s1_q_b[idx];
            #pragma unroll 8
            for (int c = 0; c < 128; ++c)
                a = fmaf(enc_op_b2[c], QWs[c * 32 + idx], a);
            C1s[idx] = a;
        }
        for (int idx = t; idx < 2048; idx += 256) {       // M1[j][m]
            int j = idx >> 5, m = idx & 31;
            float a = 0.f;
            #pragma unroll 8
            for (int c = 0; c < 128; ++c)
                a = fmaf(W2s[j * 128 + c], QWs[c * 32 + m], a);
            M1s[idx] = a;
        }
        __syncthreads();
        for (int idx = t; idx < 96; idx += 256) {         // w1ope[v][m]
            int v = idx >> 5, m = idx & 31;
            float a = s1_q_b[m];
            #pragma unroll 8
            for (int c = 0; c < 128; ++c)
                a = fmaf(OPEs[v * 128 + c], QWs[c * 32 + m], a);
            WOPs[idx] = a;
        }
        __syncthreads();
        for (int idx = t; idx < 1024; idx += 256) {       // S1[n][j]
            int n = idx >> 6, j = idx & 63;
            float a = 0.f;
            #pragma unroll 8
            for (int m = 0; m < 32; ++m)
                a = fmaf(R1s[n * 32 + m], M1s[j * 32 + m], a);
            fws[OFF_S1 + idx] = a;
        }
        for (int idx = t; idx < 16; idx += 256) {         // t1[n]
            float a = 0.f;
            #pragma unroll 8
            for (int m = 0; m < 32; ++m)
                a = fmaf(R1s[idx * 32 + m], C1s[m], a);
            fws[OFF_T1 + idx] = a;
        }
        for (int idx = t; idx < 48; idx += 256) {         // t1op[v][n]
            int v = idx / 16, n = idx % 16;
            float a = 0.f;
            #pragma unroll 8
            for (int m = 0; m < 32; ++m)
                a = fmaf(R1s[n * 32 + m], WOPs[v * 32 + m], a);
            fws[OFF_T1OP + idx] = a;
        }
        return;
    }

    // ---------------- attent2 tables: u2, V2 (+ cnt=0) ----------------
    {
        if (t < 16) cnt[t * 32] = 0;

        float* W2s = sm;           // 8192  enc_op_w2
        float* QWs = sm + 8192;    // 4096  s2_q_w (2x128x16)
        float* R2s = sm + 12288;   // 512
        float* C2s = sm + 12800;   // 32
        float* M2s = sm + 12832;   // 2048

        for (int i = t; i < 2048; i += 256)
            ((float4*)W2s)[i] = ((const float4*)enc_op_w2)[i];
        for (int i = t; i < 1024; i += 256)
            ((float4*)QWs)[i] = ((const float4*)s2_q_w)[i];
        __syncthreads();

        for (int idx = t; idx < 512; idx += 256) {
            int r = idx >> 5, n = (idx >> 4) & 1, m = idx & 15;
            float a = s2_k_b[n * 16 + m];
            #pragma unroll 8
            for (int j = 0; j < 64; ++j)
                a = fmaf(rules_emb[r * 64 + j], s2_k_w[(n * 64 + j) * 16 + m], a);
            R2s[idx] = a;
        }
        for (int idx = t; idx < 32; idx += 256) {
            int k = idx >> 4, m = idx & 15;
            float a = s2_q_b[idx];
            #pragma unroll 8
            for (int c = 0; c < 128; ++c)
                a = fmaf(enc_op_b2[c], QWs[(k * 128 + c) * 16 + m], a);
            C2s[idx] = a;
        }
        for (int idx = t; idx < 2048; idx += 256) {       // M2[k][j][m]
            int k = idx >> 10, j = (idx >> 4) & 63, m = idx & 15;
            float a = 0.f;
            #pragma unroll 8
            for (int c = 0; c < 128; ++c)
                a = fmaf(W2s[j * 128 + c], QWs[(k * 128 + c) * 16 + m], a);
            M2s[idx] = a;
        }
        __syncthreads();
        for (int idx = t; idx < 64; idx += 256) {         // u2[nk][r]
            int nk = idx >> 4, r = idx & 15, n = nk >> 1, k = nk & 1;
            float a = 0.f;
            #pragma unroll 8
            for (int m = 0; m < 16; ++m)
                a = fmaf(R2s[r * 32 + n * 16 + m], C2s[k * 16 + m], a);
            fws[OFF_U2 + idx] = a;
        }
        for (int idx = t; idx < 4096; idx += 256) {       // V2[nk][j][r]
            int nk = idx >> 10, j = (idx >> 4) & 63, r = idx & 15;
            int n = nk >> 1, k = nk & 1;
            float a = 0.f;
            #pragma unroll 8
            for (int m = 0; m < 16; ++m)
                a = fmaf(R2s[r * 32 + n * 16 + m], M2s[(k * 64 + j) * 16 + m], a);
            fws[OFF_V2 + idx] = a;
        }
    }
}

// ---------------------------------------------------------------------------
__global__ __launch_bounds__(256, 3) void stage1(
    const float* __restrict__ op1, const float* __restrict__ op2,
    const int* __restrict__ opr,
    const float* __restrict__ enc_op_w1, const float* __restrict__ enc_op_b1,
    int* __restrict__ cnt, int* __restrict__ bucket,
    float* __restrict__ fws, int B)
{
    const int t = threadIdx.x;
    const int blk = blockIdx.x;

    __shared__ float S1s[16 * 68];
    __shared__ float h[32][132];
    __shared__ float t1s[16];
    __shared__ float t1ops[48];
    __shared__ float u2s[64];
    __shared__ float bvaln[32][17];
    __shared__ float part2[4][32];
    __shared__ float o1s[32], o2s[32];
    __shared__ int ops_[32], idxr[32], idxp[32], idxc[32];
    __shared__ int lcnt[16], lpos[32], base[16];

    if (t < 32) { o1s[t] = op1[blk * 32 + t]; o2s[t] = op2[blk * 32 + t]; ops_[t] = opr[blk * 32 + t]; }
    if (t < 16) { lcnt[t] = 0; t1s[t] = fws[OFF_T1 + t]; }
    if (t >= 16 && t < 64)  t1ops[t - 16] = fws[OFF_T1OP + (t - 16)];
    if (t >= 64 && t < 128) u2s[t - 64]   = fws[OFF_U2 + (t - 64)];
    for (int i = t; i < 1024; i += 256) S1s[(i >> 6) * 68 + (i & 63)] = fws[OFF_S1 + i];
    __syncthreads();

    for (int i = t; i < 4096; i += 256) {
        int e = i >> 7, j = i & 127;
        if (j < 64) {
            h[e][j] = fmaxf(fmaf(o1s[e], enc_op_w1[j], enc_op_b1[j]), 0.f);
        } else {
            int j2 = j - 64;
            h[e][j] = fmaxf(fmaf(o2s[e], enc_op_w1[j2], enc_op_w1[64 + j2] + enc_op_b1[j2]), 0.f);
        }
    }
    __syncthreads();

    #pragma unroll
    for (int pp = 0; pp < 2; ++pp) {
        int p = t + pp * 256;
        int e = p >> 4, n = p & 15;
        float a0 = 0.f, a1 = 0.f;
        #pragma unroll 4
        for (int j4 = 0; j4 < 16; ++j4) {
            float4 s  = *(const float4*)&S1s[n * 68 + j4 * 4];
            float4 h0 = *(const float4*)&h[e][j4 * 4];
            float4 h1 = *(const float4*)&h[e][64 + j4 * 4];
            a0 = fmaf(h0.x, s.x, a0); a0 = fmaf(h0.y, s.y, a0);
            a0 = fmaf(h0.z, s.z, a0); a0 = fmaf(h0.w, s.w, a0);
            a1 = fmaf(h1.x, s.x, a1); a1 = fmaf(h1.y, s.y, a1);
            a1 = fmaf(h1.z, s.z, a1); a1 = fmaf(h1.w, s.w, a1);
        }
        bvaln[e][n] = fmaxf(t1s[n] + fmaxf(a0, a1), t1ops[ops_[e] * 16 + n]);
    }
    __syncthreads();

    if (t < 32) {
        float best = -INFINITY; int bn = 0;
        for (int n = 0; n < 16; ++n) {
            float v = bvaln[t][n];
            if (v > best) { best = v; bn = n; }
        }
        idxr[t] = bn;
    }
    __syncthreads();

    if (t < 128) {
        const int e = t & 31, nk = t >> 5, k = nk & 1;
        const int r = idxr[e];
        const float* v2p = &fws[OFF_V2 + nk * 1024 + r];
        float a = 0.f;
        #pragma unroll 4
        for (int j = 0; j < 64; ++j)
            a = fmaf(h[e][k * 64 + j], v2p[j * 16], a);
        part2[nk][e] = a + u2s[nk * 16 + r];
    }
    __syncthreads();
    if (t < 32) {
        idxp[t] = (part2[1][t] > part2[0][t]) ? 1 : 0;
        idxc[t] = (part2[3][t] > part2[2][t]) ? 1 : 0;
    }
    __syncthreads();

    for (int i = t; i < 1024; i += 256) {
        int e = i >> 5, v4 = i & 31;
        int sel = (v4 < 16) ? idxp[e] : idxc[e];
        float4 val = *(const float4*)&h[e][sel * 64 + (v4 & 15) * 4];
        *(float4*)&fws[OFF_VARH + (size_t)(blk * 32 + e) * 128 + v4 * 4] = val;
    }

    if (t < 32) lpos[t] = atomicAdd(&lcnt[idxr[t]], 1);
    __syncthreads();
    if (t < 16 && lcnt[t] > 0) base[t] = atomicAdd(&cnt[t * 32], lcnt[t]);
    __syncthreads();
    if (t < 32) {
        int r = idxr[t];
        bucket[r * B + base[r] + lpos[t]] = blk * 32 + t;
    }
}

// ---------------------------------------------------------------------------
// 64 elems/block. Single AH buffer (A -> H -> out2) + double-buffered weight
// panels with reg-staged prefetch. LDS = 33.8 + 16.4 KB -> 3 blocks/CU.
// launch_bounds(256,2) keeps acc in registers across barriers (no spill).
__global__ __launch_bounds__(256, 2) void stage2(
    const float* __restrict__ dec_w2, const float* __restrict__ dec_b2,
    const int* __restrict__ cnt, const int* __restrict__ bucket,
    const float* __restrict__ fws, float* __restrict__ out, int B)
{
    const int rule  = blockIdx.y;
    const int start = blockIdx.x * 64;
    const int count = cnt[rule * 32];
    if (start >= count) return;
    const int nelem = min(64, count - start);
    const int t = threadIdx.x;

    __shared__ float AH[64][132];   // A, then H, then relu(out2)
    __shared__ float Wp[2][2048];   // double-buffered weight panel
    __shared__ int gi[64];

    if (t < 64) gi[t] = bucket[rule * B + start + ((t < nelem) ? t : 0)];
    __syncthreads();
    for (int i = t; i < 64 * 32; i += 256) {
        int e = i >> 5, v = i & 31;
        *(float4*)&AH[e][v * 4] = *(const float4*)&fws[OFF_VARH + (size_t)gi[e] * 128 + v * 4];
    }

    const float* W1p = &fws[OFF_W1H + rule * 16384];
    // preload GEMM1 panel 0
    ((float4*)Wp[0])[t]       = ((const float4*)W1p)[t];
    ((float4*)Wp[0])[t + 256] = ((const float4*)W1p)[t + 256];
    __syncthreads();   // covers A gather + panel 0

    // ---- GEMM1: acc1 = A(64x128) @ W1h(128x128) + b1h, double-buffered panels
    const int colg1 = t & 15, rowg1 = t >> 4;   // 4 rows each
    float acc1[4][8];
    {
        const float* b1p = &fws[OFF_B1H + rule * 128 + colg1 * 8];
        #pragma unroll
        for (int i = 0; i < 4; ++i)
            #pragma unroll
            for (int j = 0; j < 8; ++j) acc1[i][j] = b1p[j];

        for (int p = 0; p < 8; ++p) {
            float4 s0, s1;
            if (p < 7) {   // issue next-panel loads; latency hides under compute
                const float4* src = (const float4*)(W1p + (p + 1) * 2048);
                s0 = src[t]; s1 = src[t + 256];
            }
            const float* Wc = Wp[p & 1];
            #pragma unroll
            for (int kk = 0; kk < 16; ++kk) {
                const int k = p * 16 + kk;
                const float4 wa = *(const float4*)&Wc[kk * 128 + colg1 * 8];
                const float4 wb = *(const float4*)&Wc[kk * 128 + colg1 * 8 + 4];
                float a0 = AH[rowg1 * 4][k], a1 = AH[rowg1 * 4 + 1][k];
                float a2 = AH[rowg1 * 4 + 2][k], a3 = AH[rowg1 * 4 + 3][k];
                acc1[0][0] = fmaf(a0, wa.x, acc1[0][0]); acc1[1][0] = fmaf(a1, wa.x, acc1[1][0]);
                acc1[2][0] = fmaf(a2, wa.x, acc1[2][0]); acc1[3][0] = fmaf(a3, wa.x, acc1[3][0]);
                acc1[0][1] = fmaf(a0, wa.y, acc1[0][1]); acc1[1][1] = fmaf(a1, wa.y, acc1[1][1]);
                acc1[2][1] = fmaf(a2, wa.y, acc1[2][1]); acc1[3][1] = fmaf(a3, wa.y, acc1[3][1]);
                acc1[0][2] = fmaf(a0, wa.z, acc1[0][2]); acc1[1][2] = fmaf(a1, wa.z, acc1[1][2]);
                acc1[2][2] = fmaf(a2, wa.z, acc1[2][2]); acc1[3][2] = fmaf(a3, wa.z, acc1[3][2]);
                acc1[0][3] = fmaf(a0, wa.w, acc1[0][3]); acc1[1][3] = fmaf(a1, wa.w, acc1[1][3]);
                acc1[2][3] = fmaf(a2, wa.w, acc1[2][3]); acc1[3][3] = fmaf(a3, wa.w, acc1[3][3]);
                acc1[0][4] = fmaf(a0, wb.x, acc1[0][4]); acc1[1][4] = fmaf(a1, wb.x, acc1[1][4]);
                acc1[2][4] = fmaf(a2, wb.x, acc1[2][4]); acc1[3][4] = fmaf(a3, wb.x, acc1[3][4]);
                acc1[0][5] = fmaf(a0, wb.y, acc1[0][5]); acc1[1][5] = fmaf(a1, wb.y, acc1[1][5]);
                acc1[2][5] = fmaf(a2, wb.y, acc1[2][5]); acc1[3][5] = fmaf(a3, wb.y, acc1[3][5]);
                acc1[0][6] = fmaf(a0, wb.z, acc1[0][6]); acc1[1][6] = fmaf(a1, wb.z, acc1[1][6]);
                acc1[2][6] = fmaf(a2, wb.z, acc1[2][6]); acc1[3][6] = fmaf(a3, wb.z, acc1[3][6]);
                acc1[0][7] = fmaf(a0, wb.w, acc1[0][7]); acc1[1][7] = fmaf(a1, wb.w, acc1[1][7]);
                acc1[2][7] = fmaf(a2, wb.w, acc1[2][7]); acc1[3][7] = fmaf(a3, wb.w, acc1[3][7]);
            }
            if (p < 7) {
                ((float4*)Wp[(p + 1) & 1])[t]       = s0;
                ((float4*)Wp[(p + 1) & 1])[t + 256] = s1;
            }
            __syncthreads();
        }
    }
    // all A reads retired at the final barrier; overwrite with H
    #pragma unroll
    for (int i = 0; i < 4; ++i)
        #pragma unroll
        for (int j = 0; j < 8; ++j)
            AH[rowg1 * 4 + i][colg1 * 8 + j] = fmaxf(acc1[i][j], 0.f);

    // preload GEMM2b panel 0 (Wp[0] reads retired at GEMM1's p=6 barrier)
    const float* W2p = &fws[OFF_W2D + rule * 8192];
    ((float4*)Wp[0])[t] = ((const float4*)W2p)[t];   // 16x64 = 256 float4
    __syncthreads();   // covers H write + panel 0

    // ---- GEMM2b: acc2 = H(64x128) @ W2d(128x64) + b2d, double-buffered
    const int colg2 = t & 7, rowg2 = t >> 3;    // 2 rows each
    float acc2[2][8];
    {
        const float* b2p = &fws[OFF_B2D + rule * 64 + colg2 * 8];
        #pragma unroll
        for (int j = 0; j < 8; ++j) { acc2[0][j] = b2p[j]; acc2[1][j] = b2p[j]; }

        for (int p = 0; p < 8; ++p) {
            float4 s0;
            if (p < 7) s0 = ((const float4*)(W2p + (p + 1) * 1024))[t];
            const float* Wc = Wp[p & 1];
            #pragma unroll
            for (int kk = 0; kk < 16; ++kk) {
                const int k = p * 16 + kk;
                const float4 wa = *(const float4*)&Wc[kk * 64 + colg2 * 8];
                const float4 wb = *(const float4*)&Wc[kk * 64 + colg2 * 8 + 4];
                float h0 = AH[rowg2 * 2][k], h1 = AH[rowg2 * 2 + 1][k];
                acc2[0][0] = fmaf(h0, wa.x, acc2[0][0]); acc2[1][0] = fmaf(h1, wa.x, acc2[1][0]);
                acc2[0][1] = fmaf(h0, wa.y, acc2[0][1]); acc2[1][1] = fmaf(h1, wa.y, acc2[1][1]);
                acc2[0][2] = fmaf(h0, wa.z, acc2[0][2]); acc2[1][2] = fmaf(h1, wa.z, acc2[1][2]);
                acc2[0][3] = fmaf(h0, wa.w, acc2[0][3]); acc2[1][3] = fmaf(h1, wa.w, acc2[1][3]);
                acc2[0][4] = fmaf(h0, wb.x, acc2[0][4]); acc2[1][4] = fmaf(h1, wb.x, acc2[1][4]);
                acc2[0][5] = fmaf(h0, wb.y, acc2[0][5]); acc2[1][5] = fmaf(h1, wb.y, acc2[1][5]);
                acc2[0][6] = fmaf(h0, wb.z, acc2[0][6]); acc2[1][6] = fmaf(h1, wb.z, acc2[1][6]);
                acc2[0][7] = fmaf(h0, wb.w, acc2[0][7]); acc2[1][7] = fmaf(h1, wb.w, acc2[1][7]);
            }
            if (p < 7) ((float4*)Wp[(p + 1) & 1])[t] = s0;
            __syncthreads();
        }
    }
    // all H reads retired; overwrite with relu(out2)
    #pragma unroll
    for (int i = 0; i < 2; ++i)
        #pragma unroll
        for (int j = 0; j < 8; ++j)
            AH[rowg2 * 2 + i][colg2 * 8 + j] = fmaxf(acc2[i][j], 0.f);
    __syncthreads();

    // ---- final: out = relu_out2 . dec_w2 + dec_b2 (wave butterfly)
    {
        const int wv = t >> 6, lane = t & 63;
        const float w2v = dec_w2[lane];
        const float b2v = dec_b2[0];
        for (int i = 0; i < 16; ++i) {
            int e = wv * 16 + i;
            if (e >= nelem) break;
            float v = AH[e][lane] * w2v;
            #pragma unroll
            for (int off = 32; off; off >>= 1) v += __shfl_down(v, off);
            if (lane == 0) out[gi[e]] = v + b2v;
        }
    }
}

// ---------------------------------------------------------------------------
extern "C" void kernel_launch(void* const* d_in, const int* in_sizes, int n_in,
                              void* d_out, int out_size, void* d_ws, size_t ws_size,
                              hipStream_t stream)
{
    const float* op1        = (const float*)d_in[0];
    const float* op2        = (const float*)d_in[1];
    const int*   opr        = (const int*)  d_in[2];
    const float* enc_op_w1  = (const float*)d_in[3];
    const float* enc_op_b1  = (const float*)d_in[4];
    const float* enc_op_w2  = (const float*)d_in[5];
    const float* enc_op_b2  = (const float*)d_in[6];
    const float* enc_opr_w1 = (const float*)d_in[7];
    const float* enc_opr_b1 = (const float*)d_in[8];
    const float* enc_opr_w2 = (const float*)d_in[9];
    const float* enc_opr_b2 = (const float*)d_in[10];
    const float* dec_w1     = (const float*)d_in[11];
    const float* dec_b1     = (const float*)d_in[12];
    const float* dec_w2     = (const float*)d_in[13];
    const float* dec_b2     = (const float*)d_in[14];
    const float* rules_emb  = (const float*)d_in[15];
    const float* rule_W1    = (const float*)d_in[16];
    const float* rule_b1    = (const float*)d_in[17];
    const float* rule_W2    = (const float*)d_in[18];
    const float* rule_b2    = (const float*)d_in[19];
    const float* s1_q_w     = (const float*)d_in[20];
    const float* s1_q_b     = (const float*)d_in[21];
    const float* s1_k_w     = (const float*)d_in[22];
    const float* s1_k_b     = (const float*)d_in[23];
    const float* s2_q_w     = (const float*)d_in[24];
    const float* s2_q_b     = (const float*)d_in[25];
    const float* s2_k_w     = (const float*)d_in[26];
    const float* s2_k_b     = (const float*)d_in[27];

    float* out = (float*)d_out;
    const int B = in_sizes[0];

    int*   cnt    = (int*)d_ws;                 // 16*32 padded counters
    int*   bucket = cnt + 16 * 32;              // 16*B
    float* fws    = (float*)(bucket + 16 * B);  // float region (16B aligned)

    prep<<<98, 256, 0, stream>>>(
        rules_emb, s1_k_w, s1_k_b, s2_k_w, s2_k_b,
        enc_opr_w1, enc_opr_b1, enc_opr_w2, enc_opr_b2,
        enc_op_w2, enc_op_b2, s1_q_w, s1_q_b, s2_q_w, s2_q_b,
        rule_W1, rule_b1, rule_W2, rule_b2, dec_w1, dec_b1, cnt, fws);

    stage1<<<B / 32, 256, 0, stream>>>(
        op1, op2, opr, enc_op_w1, enc_op_b1, cnt, bucket, fws, B);

    stage2<<<dim3(B / 64, 16), 256, 0, stream>>>(
        dec_w2, dec_b2, cnt, bucket, fws, out, B);
}